// Round 10
// baseline (1471.724 us; speedup 1.0000x reference)
//
#include <hip/hip_runtime.h>
#include <hip/hip_bf16.h>
#include <hip/hip_fp16.h>

// Per-sample slot stride in HALVES: channel-minor padded buffer [4cg][146][20][8]
#define REGH 93440
// conv6 output halves per sample: [8 cgroups][408 pos][8 ci] fp16
#define C6N 26112

typedef _Float16 v8h __attribute__((ext_vector_type(8)));
typedef float v4f __attribute__((ext_vector_type(4)));
typedef unsigned short u16x8 __attribute__((ext_vector_type(8)));

__device__ inline float h2f(unsigned short u) {
    union { unsigned short s; _Float16 h; } v; v.s = u; return (float)v.h;
}
__device__ inline unsigned short f2h(float f) {
    union { unsigned short s; _Float16 h; } v; v.h = (_Float16)f; return v.s;
}

// ---------------------------------------------------------------------------
// conv1 weight repack (fp32): [co][1][kh][kw] -> [k][co], BN folded; emits t.
// ---------------------------------------------------------------------------
__global__ void repack_k(const float* __restrict__ W, const float* __restrict__ bb,
                         const float* __restrict__ gg, const float* __restrict__ be,
                         const float* __restrict__ mm, const float* __restrict__ vv,
                         float* __restrict__ wOut, float* __restrict__ tOut,
                         int CIN, int KHW, int COUT)
{
    int gid = blockIdx.x * 256 + threadIdx.x;
    if (gid < COUT) {
        float s = gg[gid] * rsqrtf(vv[gid] + 1e-5f);
        tOut[gid] = (bb[gid] - mm[gid]) * s + be[gid];
    }
    int tot = CIN * KHW * COUT;
    if (gid >= tot) return;
    int co = gid % COUT;
    int rest = gid / COUT;
    int k = rest % KHW;
    int ci = rest / KHW;
    float s = gg[co] * rsqrtf(vv[co] + 1e-5f);
    wOut[gid] = W[(co * CIN + ci) * KHW + k] * s;
}

// ---------------------------------------------------------------------------
// MFMA B-fragment repack for 3x3 layers (conv2..conv6), fp16.
// ---------------------------------------------------------------------------
__global__ void repack_mfma_k(const float* __restrict__ W, const float* __restrict__ bb,
                              const float* __restrict__ gg, const float* __restrict__ be,
                              const float* __restrict__ mm, const float* __restrict__ vv,
                              unsigned short* __restrict__ frag, float* __restrict__ tOut,
                              int CIN, int NT, int HALVES)
{
    int gid = blockIdx.x * 256 + threadIdx.x;
    int COUT = NT * 16;
    if (gid < COUT) {
        float s = gg[gid] * rsqrtf(vv[gid] + 1e-5f);
        tOut[gid] = (bb[gid] - mm[gid]) * s + be[gid];
    }
    int tot = 9 * HALVES * NT * 512;
    if (gid >= tot) return;
    int j    = gid & 7;
    int lane = (gid >> 3) & 63;
    int nt   = (gid >> 9) % NT;
    int rest = (gid >> 9) / NT;
    int half = rest % HALVES;
    int khw  = rest / HALVES;
    int ci   = half * 32 + (lane >> 4) * 8 + j;
    int co   = nt * 16 + (lane & 15);
    int kh   = khw / 3, kw = khw % 3;
    float s = gg[co] * rsqrtf(vv[co] + 1e-5f);
    frag[gid] = f2h(W[((co * CIN + ci) * 3 + kh) * 3 + kw] * s);
}

// ---------------------------------------------------------------------------
// Conv7 weight repack into MFMA B-fragment order (12x9 kernel), fp16.
// ---------------------------------------------------------------------------
__global__ void repack7_k(const float* __restrict__ W, const float* __restrict__ bb,
                          const float* __restrict__ gg, const float* __restrict__ be,
                          const float* __restrict__ mm, const float* __restrict__ vv,
                          unsigned short* __restrict__ frag, float* __restrict__ tOut)
{
    int gid = blockIdx.x * 256 + threadIdx.x;
    if (gid < 128) {
        float s = gg[gid] * rsqrtf(vv[gid] + 1e-5f);
        tOut[gid] = (bb[gid] - mm[gid]) * s + be[gid];
    }
    if (gid >= 884736) return;           // 108*2*8*64*8
    int j    = gid & 7;
    int lane = (gid >> 3) & 63;
    int nt   = (gid >> 9) & 7;
    int half = (gid >> 12) & 1;
    int khw  = gid >> 13;
    int co   = nt * 16 + (lane & 15);
    int ci   = half * 32 + (lane >> 4) * 8 + j;
    int kh   = khw / 9, kw = khw - kh * 9;
    float s = gg[co] * rsqrtf(vv[co] + 1e-5f);
    frag[gid] = f2h(W[((co * 64 + ci) * 12 + kh) * 9 + kw] * s);
}

// ---------------------------------------------------------------------------
// Zero pad rings of both ping-pong buffers (once per call: rings persist
// across chunks — interior writes never touch them).
// ---------------------------------------------------------------------------
__global__ void zero_rings_k(unsigned short* __restrict__ bufA,
                             unsigned short* __restrict__ bufB, int cn)
{
    int gid = blockIdx.x * 256 + threadIdx.x;
    int tot = cn * 2 * 4 * 328;
    if (gid >= tot) return;
    int e = gid % 328;
    int rest = gid / 328;
    int cg = rest % 4; rest /= 4;
    int bsel = rest & 1;
    int nl = rest >> 1;
    unsigned short* base = (bsel ? bufB : bufA) + (size_t)nl * REGH + cg * 23360;
    int row, col;
    if (e < 40) { row = (e < 20) ? 0 : 145; col = (e < 20) ? e : e - 20; }
    else { int e2 = e - 40; row = 1 + (e2 >> 1); col = (e2 & 1) ? 16 : 0; }
    *(u16x8*)(base + (row * 20 + col) * 8) = (u16x8){0,0,0,0,0,0,0,0};
}

// ---------------------------------------------------------------------------
// Conv1: 1 -> 32 channels, 3x3 SAME, channel-minor padded output.
// ---------------------------------------------------------------------------
__global__ __launch_bounds__(256) void conv1_k(
    const float* __restrict__ x, unsigned short* __restrict__ out,
    const float* __restrict__ wr, const float* __restrict__ tv,
    int c0, int cn)
{
    int gid = blockIdx.x * 256 + threadIdx.x;
    if (gid >= cn * 2160) return;
    int nl = gid / 2160, p = gid - nl * 2160;
    int f = p / 15, w = p - f * 15;
    int n = c0 + nl;
    int b = n / 108, t = n - b * 108;

    float acc[32];
#pragma unroll
    for (int i = 0; i < 32; ++i) acc[i] = 0.f;

    for (int kh = 0; kh < 3; ++kh) {
        int ff = f + kh - 1;
        if (ff < 0 || ff >= 144) continue;
        for (int kw = 0; kw < 3; ++kw) {
            int c = w + kw - 1;
            if (c < 0 || c >= 15) continue;
            int tt = t + c - 7;
            if (tt < 0 || tt >= 108) continue;
            float xval = x[(b * 108 + tt) * 144 + ff];
            const float* wp = wr + (kh * 3 + kw) * 32;
#pragma unroll
            for (int q = 0; q < 8; ++q) {
                float4 wv = *(const float4*)(wp + q * 4);
                acc[q * 4 + 0] = fmaf(xval, wv.x, acc[q * 4 + 0]);
                acc[q * 4 + 1] = fmaf(xval, wv.y, acc[q * 4 + 1]);
                acc[q * 4 + 2] = fmaf(xval, wv.z, acc[q * 4 + 2]);
                acc[q * 4 + 3] = fmaf(xval, wv.w, acc[q * 4 + 3]);
            }
        }
    }
    unsigned short* ob = out + (size_t)nl * REGH + ((f + 1) * 20 + (w + 1)) * 8;
#pragma unroll
    for (int cg = 0; cg < 4; ++cg) {
        u16x8 pk;
#pragma unroll
        for (int c = 0; c < 8; ++c)
            pk[c] = f2h(fmaxf(acc[cg * 8 + c] + tv[cg * 8 + c], 0.f));
        *(u16x8*)(ob + cg * 23360) = pk;
    }
}

// ---------------------------------------------------------------------------
// conv2/3/4 as MFMA implicit GEMM (unchanged R9: LDS-staged band slab).
// ---------------------------------------------------------------------------
template<bool POOL>
__global__ __launch_bounds__(256) void conv234m_k(
    const unsigned short* __restrict__ in, unsigned short* __restrict__ out,
    const unsigned short* __restrict__ frag, const float* __restrict__ tv)
{
    __shared__ __align__(16) unsigned short sA[11552];  // 4 x 361 x 8
    const int band = blockIdx.x;
    const int n = blockIdx.y;
    const int tid = threadIdx.x;
    const int wave = tid >> 6, lane = tid & 63;
    const int m = lane & 15, quad = lane >> 4;

    {
        const float4* src = (const float4*)(in + (size_t)n * REGH);
        float4* dst = (float4*)sA;
        for (int i = tid; i < 1440; i += 256) {
            int q = i / 360, pos = i - q * 360;
            dst[q * 361 + pos] = src[q * 2920 + band * 320 + pos];
        }
    }
    __syncthreads();

    int mt[4], la0[4];
#pragma unroll
    for (int wt = 0; wt < 4; ++wt) {
        int t = wave * 4 + wt; if (t > 14) t = 14;
        mt[wt] = t;
        int p = band * 240 + t * 16 + m;
        int r, w;
        if (POOL) { int pr = p / 30, rem = p - pr * 30; w = rem >> 1; r = pr * 2 + (rem & 1); }
        else      { r = p / 15; w = p - r * 15; }
        la0[wt] = ((r - band * 16) * 20 + w) * 8;
    }

    v4f acc[2][4];
#pragma unroll
    for (int nt = 0; nt < 2; ++nt)
#pragma unroll
        for (int wt = 0; wt < 4; ++wt) acc[nt][wt] = (v4f){0.f,0.f,0.f,0.f};

    const unsigned short* sQ = sA + quad * 361 * 8;
#pragma unroll
    for (int khw = 0; khw < 9; ++khw) {
        const int shift = ((khw / 3) * 20 + (khw % 3)) * 8;
        v8h a[4];
#pragma unroll
        for (int wt = 0; wt < 4; ++wt)
            a[wt] = *(const v8h*)(sQ + la0[wt] + shift);
#pragma unroll
        for (int nt = 0; nt < 2; ++nt) {
            v8h b = *(const v8h*)(frag + (khw * 2 + nt) * 512 + lane * 8);
#pragma unroll
            for (int wt = 0; wt < 4; ++wt)
                acc[nt][wt] = __builtin_amdgcn_mfma_f32_16x16x32_f16(a[wt], b, acc[nt][wt], 0, 0, 0);
        }
    }

    unsigned short* outN = out + (size_t)n * REGH;
#pragma unroll
    for (int wt = 0; wt < 4; ++wt) {
        const int pb = band * 240 + mt[wt] * 16 + quad * 4;
#pragma unroll
        for (int nt = 0; nt < 2; ++nt) {
            const int co = nt * 16 + m;
            const float tb = tv[co];
            unsigned short* ob = outN + (co >> 3) * (POOL ? 9216 : 23360) + (co & 7);
            if (POOL) {
#pragma unroll
                for (int pi = 0; pi < 2; ++pi) {
                    int pe = pb + pi * 2;
                    int pr = pe / 30, rem = pe - pr * 30, w = rem >> 1;
                    float v0 = fmaxf(acc[nt][wt][pi * 2] + tb, 0.f);
                    float v1 = fmaxf(acc[nt][wt][pi * 2 + 1] + tb, 0.f);
                    ob[(pr * 16 + w) * 8] = f2h(fmaxf(v0, v1));
                }
            } else {
#pragma unroll
                for (int reg = 0; reg < 4; ++reg) {
                    int pr = pb + reg;
                    int f = pr / 15, w = pr - f * 15;
                    ob[((f + 1) * 20 + (w + 1)) * 8] = f2h(fmaxf(acc[nt][wt][reg] + tb, 0.f));
                }
            }
        }
    }
}

// ---------------------------------------------------------------------------
// conv5 MFMA: 32->64ch 3x3 VALID (unchanged R8/R9).
// ---------------------------------------------------------------------------
__global__ __launch_bounds__(256) void conv5m_k(
    const unsigned short* __restrict__ in, unsigned short* __restrict__ out,
    const unsigned short* __restrict__ frag, const float* __restrict__ tv)
{
    const int n = blockIdx.y;
    const int tid = threadIdx.x;
    const int wave = tid >> 6, lane = tid & 63;
    const int m = lane & 15, quad = lane >> 4;
    const unsigned short* inN = in + (size_t)n * REGH + quad * 9216;

    int mt[2], a0[2];
#pragma unroll
    for (int wt = 0; wt < 2; ++wt) {
        int t = blockIdx.x * 8 + wave * 2 + wt; if (t > 56) t = 56;
        mt[wt] = t;
        int p = t * 16 + m; if (p > 909) p = 909;
        int r = p / 13, w = p - r * 13;
        a0[wt] = (r * 16 + w) * 8;
    }

    v4f acc[4][2];
#pragma unroll
    for (int nt = 0; nt < 4; ++nt)
#pragma unroll
        for (int wt = 0; wt < 2; ++wt) acc[nt][wt] = (v4f){0.f,0.f,0.f,0.f};

#pragma unroll
    for (int khw = 0; khw < 9; ++khw) {
        const int shift = ((khw / 3) * 16 + (khw % 3)) * 8;
        v8h a[2];
#pragma unroll
        for (int wt = 0; wt < 2; ++wt)
            a[wt] = *(const v8h*)(inN + a0[wt] + shift);
#pragma unroll
        for (int nt = 0; nt < 4; ++nt) {
            v8h b = *(const v8h*)(frag + (khw * 4 + nt) * 512 + lane * 8);
#pragma unroll
            for (int wt = 0; wt < 2; ++wt)
                acc[nt][wt] = __builtin_amdgcn_mfma_f32_16x16x32_f16(a[wt], b, acc[nt][wt], 0, 0, 0);
        }
    }

    unsigned short* outN = out + (size_t)n * REGH;
#pragma unroll
    for (int wt = 0; wt < 2; ++wt) {
        const int pb = mt[wt] * 16 + quad * 4;
#pragma unroll
        for (int nt = 0; nt < 4; ++nt) {
            const int co = nt * 16 + m;
            const float tb = tv[co];
            unsigned short* ob = outN + (co >> 3) * 8960 + (co & 7);
#pragma unroll
            for (int reg = 0; reg < 4; ++reg) {
                int p = pb + reg;
                if (p < 910) {
                    int r = p / 13, w = p - r * 13;
                    ob[(r * 16 + w) * 8] = f2h(fmaxf(acc[nt][wt][reg] + tb, 0.f));
                }
            }
        }
    }
}

// ---------------------------------------------------------------------------
// conv6 MFMA (+fused pool) -> c6 (unchanged R8/R9).
// ---------------------------------------------------------------------------
__global__ __launch_bounds__(256) void conv6m_k(
    const unsigned short* __restrict__ in, unsigned short* __restrict__ c6,
    const unsigned short* __restrict__ frag, const float* __restrict__ tv)
{
    const int n = blockIdx.y;
    const int tid = threadIdx.x;
    const int wave = tid >> 6, lane = tid & 63;
    const int m = lane & 15, quad = lane >> 4;
    const unsigned short* inN = in + (size_t)n * REGH;

    int mt[2], a0[2];
#pragma unroll
    for (int wt = 0; wt < 2; ++wt) {
        int t = blockIdx.x * 8 + wave * 2 + wt; if (t > 46) t = 46;
        mt[wt] = t;
        int p = t * 16 + m; if (p > 747) p = 747;
        int pr = p / 22, rem = p - pr * 22;
        int w = rem >> 1, r = pr * 2 + (rem & 1);
        a0[wt] = (r * 16 + w) * 8;
    }

    v4f acc[4][2];
#pragma unroll
    for (int nt = 0; nt < 4; ++nt)
#pragma unroll
        for (int wt = 0; wt < 2; ++wt) acc[nt][wt] = (v4f){0.f,0.f,0.f,0.f};

#pragma unroll
    for (int khw = 0; khw < 9; ++khw) {
        const int shift = ((khw / 3) * 16 + (khw % 3)) * 8;
#pragma unroll
        for (int half = 0; half < 2; ++half) {
            const unsigned short* ip = inN + (half * 4 + quad) * 8960 + shift;
            v8h a[2];
#pragma unroll
            for (int wt = 0; wt < 2; ++wt)
                a[wt] = *(const v8h*)(ip + a0[wt]);
#pragma unroll
            for (int nt = 0; nt < 4; ++nt) {
                v8h b = *(const v8h*)(frag + ((khw * 2 + half) * 4 + nt) * 512 + lane * 8);
#pragma unroll
                for (int wt = 0; wt < 2; ++wt)
                    acc[nt][wt] = __builtin_amdgcn_mfma_f32_16x16x32_f16(a[wt], b, acc[nt][wt], 0, 0, 0);
            }
        }
    }

    unsigned short* outN = c6 + (size_t)n * C6N;
#pragma unroll
    for (int wt = 0; wt < 2; ++wt) {
        const int pb = mt[wt] * 16 + quad * 4;
#pragma unroll
        for (int nt = 0; nt < 4; ++nt) {
            const int co = nt * 16 + m;
            const float tb = tv[co];
            unsigned short* ob = outN + (co >> 3) * 3264 + (co & 7);
#pragma unroll
            for (int pi = 0; pi < 2; ++pi) {
                int pe = pb + pi * 2;
                if (pe < 748) {
                    int pr = pe / 22, rem = pe - pr * 22, w = rem >> 1;
                    float v0 = fmaxf(acc[nt][wt][pi * 2] + tb, 0.f);
                    float v1 = fmaxf(acc[nt][wt][pi * 2 + 1] + tb, 0.f);
                    ob[(pr * 12 + w) * 8] = f2h(fmaxf(v0, v1));
                }
            }
        }
    }
}

// ---------------------------------------------------------------------------
// Conv7 MFMA GEMM, K x N wave-split. M=69(->80), N=128, K=6912.
// Waves: ks=wave>>1 splits khw (0..53 / 54..107), ns=wave&1 splits N (co
// 0..63 / 64..127). Each wave: 4 N-tiles x 5 M-tiles = 20 MFMA per K-step vs
// 5 A ds_read_b128 -> MFMA-paced (R9 was LDS-paced: 4 waves re-read the same
// A, 60cyc LDS vs 48cyc MFMA). ks=1 waves write partials to LDS (40KB,
// aliased over sA); ks=0 waves combine + bias/relu/mean (pre-ReLU combine
// required for correctness).
// ---------------------------------------------------------------------------
__global__ __launch_bounds__(256) void conv7mfma_k(
    const unsigned short* __restrict__ c6, float* __restrict__ pooled,
    const unsigned short* __restrict__ frag7, const float* __restrict__ tv)
{
    __shared__ __align__(16) unsigned char smem[40960];
    unsigned short* sA = (unsigned short*)smem;   // 4 x 443 x 8 halves (28352B)
    float* sC = (float*)smem;                     // 2 x 20 x 64 x 4 f32 (40960B)
    const int n = blockIdx.x;
    const int tid = threadIdx.x;
    const int wave = tid >> 6;
    const int lane = tid & 63;
    const int m = lane & 15;
    const int quad = lane >> 4;
    const int ks = wave >> 1;
    const int ns = wave & 1;

    int pm[5];
#pragma unroll
    for (int mt = 0; mt < 5; ++mt) {
        int p = mt * 16 + m;
        if (p >= 69) p = 0;
        pm[mt] = (p / 3) * 13 + (p % 3);
    }

    v4f acc[4][5];
#pragma unroll
    for (int t = 0; t < 4; ++t)
#pragma unroll
        for (int mt = 0; mt < 5; ++mt)
            acc[t][mt] = (v4f){0.f, 0.f, 0.f, 0.f};

    for (int half = 0; half < 2; ++half) {
        __syncthreads();
        {
            const float4* src = (const float4*)(c6 + (size_t)n * C6N + half * 13056);
            float4* dst = (float4*)sA;
            for (int i = tid; i < 1632; i += 256) {
                int q = i / 408, pos = i - q * 408;
                int h = pos / 12, w = pos - h * 12;
                dst[q * 443 + h * 13 + w] = src[i];
            }
        }
        __syncthreads();
        for (int kk = 0; kk < 54; ++kk) {
            const int khw = ks * 54 + kk;
            const int off = (khw / 9) * 13 + (khw % 9);
            v8h a[5];
#pragma unroll
            for (int mt = 0; mt < 5; ++mt)
                a[mt] = *(const v8h*)(sA + (quad * 443 + pm[mt] + off) * 8);
            const unsigned short* bp = frag7
                + ((size_t)((khw * 2 + half) * 8 + ns * 4)) * 512 + lane * 8;
#pragma unroll
            for (int t = 0; t < 4; ++t) {
                v8h b = *(const v8h*)(bp + t * 512);
#pragma unroll
                for (int mt = 0; mt < 5; ++mt)
                    acc[t][mt] = __builtin_amdgcn_mfma_f32_16x16x32_f16(
                        a[mt], b, acc[t][mt], 0, 0, 0);
            }
        }
    }

    // Combine ks halves via LDS, then epilogue on ks==0 waves.
    __syncthreads();
    if (ks == 1) {
#pragma unroll
        for (int t = 0; t < 4; ++t)
#pragma unroll
            for (int mt = 0; mt < 5; ++mt)
                *(v4f*)(sC + (((ns * 20) + t * 5 + mt) * 64 + lane) * 4) = acc[t][mt];
    }
    __syncthreads();
    if (ks == 0) {
        float s[4] = {0.f, 0.f, 0.f, 0.f};
#pragma unroll
        for (int t = 0; t < 4; ++t) {
            const float tb = tv[ns * 64 + t * 16 + m];
#pragma unroll
            for (int mt = 0; mt < 5; ++mt) {
                v4f pc = *(const v4f*)(sC + (((ns * 20) + t * 5 + mt) * 64 + lane) * 4);
#pragma unroll
                for (int rr = 0; rr < 4; ++rr) {
                    int p = mt * 16 + quad * 4 + rr;
                    if (p < 69) s[t] += fmaxf(acc[t][mt][rr] + pc[rr] + tb, 0.f);
                }
            }
        }
#pragma unroll
        for (int t = 0; t < 4; ++t) {
            s[t] += __shfl_xor(s[t], 16);
            s[t] += __shfl_xor(s[t], 32);
        }
        if (lane < 16) {
#pragma unroll
            for (int t = 0; t < 4; ++t)
                pooled[(size_t)n * 128 + ns * 64 + t * 16 + lane] = s[t] * (1.f / 69.f);
        }
    }
}

// ---------------------------------------------------------------------------
// logits = b8 + W8(25x128) . pooled
// ---------------------------------------------------------------------------
__global__ void logits_k(const float* __restrict__ pooled, const float* __restrict__ W8,
                         const float* __restrict__ b8, float* __restrict__ outg,
                         int total)
{
    int gid = blockIdx.x * 256 + threadIdx.x;
    if (gid >= total * 25) return;
    int nl = gid / 25, c = gid - nl * 25;
    const float* pp = pooled + (size_t)nl * 128;
    const float* wp = W8 + c * 128;
    float s = b8[c];
#pragma unroll
    for (int ci = 0; ci < 128; ci += 4) {
        float4 wv = *(const float4*)(wp + ci);
        float4 pv = *(const float4*)(pp + ci);
        s = fmaf(wv.x, pv.x, s);
        s = fmaf(wv.y, pv.y, s);
        s = fmaf(wv.z, pv.z, s);
        s = fmaf(wv.w, pv.w, s);
    }
    outg[(size_t)nl * 25 + c] = s;
}

// ---------------------------------------------------------------------------
extern "C" void kernel_launch(void* const* d_in, const int* in_sizes, int n_in,
                              void* d_out, int out_size, void* d_ws, size_t ws_size,
                              hipStream_t stream)
{
    const float* x = (const float*)d_in[0];
    const float* Wl[8]; const float* bl[8]; const float* gl[8];
    const float* bel[8]; const float* ml[8]; const float* vl[8];
    for (int i = 1; i <= 7; ++i) {
        int o = 2 + (i - 1) * 6;
        Wl[i]  = (const float*)d_in[o + 0];
        bl[i]  = (const float*)d_in[o + 1];
        gl[i]  = (const float*)d_in[o + 2];
        bel[i] = (const float*)d_in[o + 3];
        ml[i]  = (const float*)d_in[o + 4];
        vl[i]  = (const float*)d_in[o + 5];
    }
    const float* W8 = (const float*)d_in[44];
    const float* b8 = (const float*)d_in[45];
    float* ws = (float*)d_ws;

    // Workspace layout (float offsets); all 16B aligned.
    float* wr1 = ws + 0;        float* t1 = ws + 288;
    unsigned short* f2b = (unsigned short*)(ws + 320);
    float* t2 = ws + 4928;
    unsigned short* f3b = (unsigned short*)(ws + 4960);
    float* t3 = ws + 9568;
    unsigned short* f4b = (unsigned short*)(ws + 9600);
    float* t4 = ws + 14208;
    unsigned short* f5b = (unsigned short*)(ws + 14240);
    float* t5 = ws + 23456;
    unsigned short* f6b = (unsigned short*)(ws + 23520);
    float* t6 = ws + 41952;
    unsigned short* f7b = (unsigned short*)(ws + 42016);
    float* t7 = ws + 484384;
    const size_t WFL = 484512;

    // Persistent: c6 ([n][8][408][8] fp16) + pooled (fp32).
    unsigned short* c6buf = (unsigned short*)(ws + WFL);
    const size_t C6FL = (size_t)1728 * C6N / 2;
    float* pooled = ws + WFL + C6FL;
    const size_t FIXED = WFL + C6FL + (size_t)1728 * 128;

    size_t avail_fl = ws_size / 4;
    size_t buf_halves = (avail_fl > FIXED) ? (avail_fl - FIXED) * 2 : 0;
    int Cs = (int)(buf_halves / (2 * (size_t)REGH));
    if (Cs < 1) Cs = 1;
    if (Cs > 1728) Cs = 1728;
    unsigned short* bufA = (unsigned short*)(ws + FIXED);
    unsigned short* bufB = bufA + (size_t)Cs * REGH;

    auto g1 = [](int t) { return (t + 255) / 256; };

    // Weight repacks (once per call)
    repack_k<<<g1(288), 256, 0, stream>>>(Wl[1], bl[1], gl[1], bel[1], ml[1], vl[1], wr1, t1, 1, 9, 32);
    repack_mfma_k<<<g1(9216),  256, 0, stream>>>(Wl[2], bl[2], gl[2], bel[2], ml[2], vl[2], f2b, t2, 32, 2, 1);
    repack_mfma_k<<<g1(9216),  256, 0, stream>>>(Wl[3], bl[3], gl[3], bel[3], ml[3], vl[3], f3b, t3, 32, 2, 1);
    repack_mfma_k<<<g1(9216),  256, 0, stream>>>(Wl[4], bl[4], gl[4], bel[4], ml[4], vl[4], f4b, t4, 32, 2, 1);
    repack_mfma_k<<<g1(18432), 256, 0, stream>>>(Wl[5], bl[5], gl[5], bel[5], ml[5], vl[5], f5b, t5, 32, 4, 1);
    repack_mfma_k<<<g1(36864), 256, 0, stream>>>(Wl[6], bl[6], gl[6], bel[6], ml[6], vl[6], f6b, t6, 64, 4, 2);
    repack7_k<<<g1(884736), 256, 0, stream>>>(Wl[7], bl[7], gl[7], bel[7], ml[7], vl[7], f7b, t7);

    // Ring zeros once per call (rings persist across chunks).
    zero_rings_k<<<g1(Cs * 2624), 256, 0, stream>>>(bufA, bufB, Cs);

    // Stage 1 (chunked): conv1..conv6 (all MFMA except conv1)
    for (int c0 = 0; c0 < 1728; c0 += Cs) {
        int cn = (1728 - c0 < Cs) ? (1728 - c0) : Cs;
        conv1_k<<<g1(cn * 2160), 256, 0, stream>>>(x, bufA, wr1, t1, c0, cn);
        conv234m_k<false><<<dim3(9, cn), 256, 0, stream>>>(bufA, bufB, f2b, t2);
        conv234m_k<false><<<dim3(9, cn), 256, 0, stream>>>(bufB, bufA, f3b, t3);
        conv234m_k<true ><<<dim3(9, cn), 256, 0, stream>>>(bufA, bufB, f4b, t4);
        conv5m_k<<<dim3(8, cn), 256, 0, stream>>>(bufB, bufA, f5b, t5);
        conv6m_k<<<dim3(6, cn), 256, 0, stream>>>(bufA, c6buf + (size_t)c0 * C6N, f6b, t6);
    }

    // Stage 2: conv7 MFMA (+bias+relu+mean) over all samples, then logits.
    conv7mfma_k<<<1728, 256, 0, stream>>>(c6buf, pooled, f7b, t7);
    logits_k<<<g1(1728 * 25), 256, 0, stream>>>(pooled, W8, b8, (float*)d_out, 1728);
}

// Round 11
// 1350.436 us; speedup vs baseline: 1.0898x; 1.0898x over previous
//
#include <hip/hip_runtime.h>
#include <hip/hip_bf16.h>
#include <hip/hip_fp16.h>

// Per-sample slot stride in HALVES: channel-minor padded buffer [4cg][146][17][8]
#define REGH 79424
#define CGS1 19856     // per-cgroup stride (146*17*8)
// conv6 output halves per sample: [8 cgroups][408 pos][8 ci] fp16
#define C6N 26112

typedef _Float16 v8h __attribute__((ext_vector_type(8)));
typedef float v4f __attribute__((ext_vector_type(4)));
typedef unsigned short u16x8 __attribute__((ext_vector_type(8)));

__device__ inline float h2f(unsigned short u) {
    union { unsigned short s; _Float16 h; } v; v.s = u; return (float)v.h;
}
__device__ inline unsigned short f2h(float f) {
    union { unsigned short s; _Float16 h; } v; v.h = (_Float16)f; return v.s;
}

// ---------------------------------------------------------------------------
// conv1 weight repack (fp32): [co][1][kh][kw] -> [k][co], BN folded; emits t.
// ---------------------------------------------------------------------------
__global__ void repack_k(const float* __restrict__ W, const float* __restrict__ bb,
                         const float* __restrict__ gg, const float* __restrict__ be,
                         const float* __restrict__ mm, const float* __restrict__ vv,
                         float* __restrict__ wOut, float* __restrict__ tOut,
                         int CIN, int KHW, int COUT)
{
    int gid = blockIdx.x * 256 + threadIdx.x;
    if (gid < COUT) {
        float s = gg[gid] * rsqrtf(vv[gid] + 1e-5f);
        tOut[gid] = (bb[gid] - mm[gid]) * s + be[gid];
    }
    int tot = CIN * KHW * COUT;
    if (gid >= tot) return;
    int co = gid % COUT;
    int rest = gid / COUT;
    int k = rest % KHW;
    int ci = rest / KHW;
    float s = gg[co] * rsqrtf(vv[co] + 1e-5f);
    wOut[gid] = W[(co * CIN + ci) * KHW + k] * s;
}

// ---------------------------------------------------------------------------
// MFMA B-fragment repack for 3x3 layers (conv2..conv6), fp16.
// ---------------------------------------------------------------------------
__global__ void repack_mfma_k(const float* __restrict__ W, const float* __restrict__ bb,
                              const float* __restrict__ gg, const float* __restrict__ be,
                              const float* __restrict__ mm, const float* __restrict__ vv,
                              unsigned short* __restrict__ frag, float* __restrict__ tOut,
                              int CIN, int NT, int HALVES)
{
    int gid = blockIdx.x * 256 + threadIdx.x;
    int COUT = NT * 16;
    if (gid < COUT) {
        float s = gg[gid] * rsqrtf(vv[gid] + 1e-5f);
        tOut[gid] = (bb[gid] - mm[gid]) * s + be[gid];
    }
    int tot = 9 * HALVES * NT * 512;
    if (gid >= tot) return;
    int j    = gid & 7;
    int lane = (gid >> 3) & 63;
    int nt   = (gid >> 9) % NT;
    int rest = (gid >> 9) / NT;
    int half = rest % HALVES;
    int khw  = rest / HALVES;
    int ci   = half * 32 + (lane >> 4) * 8 + j;
    int co   = nt * 16 + (lane & 15);
    int kh   = khw / 3, kw = khw % 3;
    float s = gg[co] * rsqrtf(vv[co] + 1e-5f);
    frag[gid] = f2h(W[((co * CIN + ci) * 3 + kh) * 3 + kw] * s);
}

// ---------------------------------------------------------------------------
// Conv7 weight repack into MFMA B-fragment order (12x9 kernel), fp16.
// ---------------------------------------------------------------------------
__global__ void repack7_k(const float* __restrict__ W, const float* __restrict__ bb,
                          const float* __restrict__ gg, const float* __restrict__ be,
                          const float* __restrict__ mm, const float* __restrict__ vv,
                          unsigned short* __restrict__ frag, float* __restrict__ tOut)
{
    int gid = blockIdx.x * 256 + threadIdx.x;
    if (gid < 128) {
        float s = gg[gid] * rsqrtf(vv[gid] + 1e-5f);
        tOut[gid] = (bb[gid] - mm[gid]) * s + be[gid];
    }
    if (gid >= 884736) return;           // 108*2*8*64*8
    int j    = gid & 7;
    int lane = (gid >> 3) & 63;
    int nt   = (gid >> 9) & 7;
    int half = (gid >> 12) & 1;
    int khw  = gid >> 13;
    int co   = nt * 16 + (lane & 15);
    int ci   = half * 32 + (lane >> 4) * 8 + j;
    int kh   = khw / 9, kw = khw - kh * 9;
    float s = gg[co] * rsqrtf(vv[co] + 1e-5f);
    frag[gid] = f2h(W[((co * 64 + ci) * 12 + kh) * 9 + kw] * s);
}

// ---------------------------------------------------------------------------
// Zero pad rings (once per call: rings persist across chunks).
// Rows 0/145 full 17 cols; rows 1..144 cols {0,16}. 322 elems per cg.
// ---------------------------------------------------------------------------
__global__ void zero_rings_k(unsigned short* __restrict__ bufA,
                             unsigned short* __restrict__ bufB, int cn)
{
    int gid = blockIdx.x * 256 + threadIdx.x;
    int tot = cn * 2 * 4 * 322;
    if (gid >= tot) return;
    int e = gid % 322;
    int rest = gid / 322;
    int cg = rest % 4; rest /= 4;
    int bsel = rest & 1;
    int nl = rest >> 1;
    unsigned short* base = (bsel ? bufB : bufA) + (size_t)nl * REGH + cg * CGS1;
    int row, col;
    if (e < 34) { row = (e < 17) ? 0 : 145; col = (e < 17) ? e : e - 17; }
    else { int e2 = e - 34; row = 1 + (e2 >> 1); col = (e2 & 1) ? 16 : 0; }
    *(u16x8*)(base + (row * 17 + col) * 8) = (u16x8){0,0,0,0,0,0,0,0};
}

// ---------------------------------------------------------------------------
// Conv1: 1 -> 32 channels, 3x3 SAME, channel-minor padded output.
// Two zero paddings on the window axis: conv SAME pad at cols -1/15 (always
// zero) and the T-padding (zero when t+c-7 outside [0,108)).
// ---------------------------------------------------------------------------
__global__ __launch_bounds__(256) void conv1_k(
    const float* __restrict__ x, unsigned short* __restrict__ out,
    const float* __restrict__ wr, const float* __restrict__ tv,
    int c0, int cn)
{
    int gid = blockIdx.x * 256 + threadIdx.x;
    if (gid >= cn * 2160) return;
    int nl = gid / 2160, p = gid - nl * 2160;
    int f = p / 15, w = p - f * 15;
    int n = c0 + nl;
    int b = n / 108, t = n - b * 108;

    float acc[32];
#pragma unroll
    for (int i = 0; i < 32; ++i) acc[i] = 0.f;

    for (int kh = 0; kh < 3; ++kh) {
        int ff = f + kh - 1;
        if (ff < 0 || ff >= 144) continue;
        for (int kw = 0; kw < 3; ++kw) {
            int c = w + kw - 1;
            if (c < 0 || c >= 15) continue;
            int tt = t + c - 7;
            if (tt < 0 || tt >= 108) continue;
            float xval = x[(b * 108 + tt) * 144 + ff];
            const float* wp = wr + (kh * 3 + kw) * 32;
#pragma unroll
            for (int q = 0; q < 8; ++q) {
                float4 wv = *(const float4*)(wp + q * 4);
                acc[q * 4 + 0] = fmaf(xval, wv.x, acc[q * 4 + 0]);
                acc[q * 4 + 1] = fmaf(xval, wv.y, acc[q * 4 + 1]);
                acc[q * 4 + 2] = fmaf(xval, wv.z, acc[q * 4 + 2]);
                acc[q * 4 + 3] = fmaf(xval, wv.w, acc[q * 4 + 3]);
            }
        }
    }
    unsigned short* ob = out + (size_t)nl * REGH + ((f + 1) * 17 + (w + 1)) * 8;
#pragma unroll
    for (int cg = 0; cg < 4; ++cg) {
        u16x8 pk;
#pragma unroll
        for (int c = 0; c < 8; ++c)
            pk[c] = f2h(fmaxf(acc[cg * 8 + c] + tv[cg * 8 + c], 0.f));
        *(u16x8*)(ob + cg * CGS1) = pk;
    }
}

// ---------------------------------------------------------------------------
// conv2/3/4 as MFMA implicit GEMM, LDS-staged band slab, pad-17 layout.
// Slab: 4 quads x 18 rows x 17 cols (float4 each) with quad stride 307 (odd).
// ---------------------------------------------------------------------------
template<bool POOL>
__global__ __launch_bounds__(256) void conv234m_k(
    const unsigned short* __restrict__ in, unsigned short* __restrict__ out,
    const unsigned short* __restrict__ frag, const float* __restrict__ tv)
{
    __shared__ __align__(16) unsigned short sA[9824];  // 4 x 307 x 8
    const int band = blockIdx.x;
    const int n = blockIdx.y;
    const int tid = threadIdx.x;
    const int wave = tid >> 6, lane = tid & 63;
    const int m = lane & 15, quad = lane >> 4;

    {
        const float4* src = (const float4*)(in + (size_t)n * REGH);
        float4* dst = (float4*)sA;
        for (int i = tid; i < 1224; i += 256) {
            int q = i / 306, pos = i - q * 306;
            dst[q * 307 + pos] = src[q * 2482 + band * 272 + pos];
        }
    }
    __syncthreads();

    int mt[4], la0[4];
#pragma unroll
    for (int wt = 0; wt < 4; ++wt) {
        int t = wave * 4 + wt; if (t > 14) t = 14;
        mt[wt] = t;
        int p = band * 240 + t * 16 + m;
        int r, w;
        if (POOL) { int pr = p / 30, rem = p - pr * 30; w = rem >> 1; r = pr * 2 + (rem & 1); }
        else      { r = p / 15; w = p - r * 15; }
        la0[wt] = ((r - band * 16) * 17 + w) * 8;
    }

    v4f acc[2][4];
#pragma unroll
    for (int nt = 0; nt < 2; ++nt)
#pragma unroll
        for (int wt = 0; wt < 4; ++wt) acc[nt][wt] = (v4f){0.f,0.f,0.f,0.f};

    const unsigned short* sQ = sA + quad * 307 * 8;
#pragma unroll
    for (int khw = 0; khw < 9; ++khw) {
        const int shift = ((khw / 3) * 17 + (khw % 3)) * 8;
        v8h a[4];
#pragma unroll
        for (int wt = 0; wt < 4; ++wt)
            a[wt] = *(const v8h*)(sQ + la0[wt] + shift);
#pragma unroll
        for (int nt = 0; nt < 2; ++nt) {
            v8h b = *(const v8h*)(frag + (khw * 2 + nt) * 512 + lane * 8);
#pragma unroll
            for (int wt = 0; wt < 4; ++wt)
                acc[nt][wt] = __builtin_amdgcn_mfma_f32_16x16x32_f16(a[wt], b, acc[nt][wt], 0, 0, 0);
        }
    }

    unsigned short* outN = out + (size_t)n * REGH;
#pragma unroll
    for (int wt = 0; wt < 4; ++wt) {
        const int pb = band * 240 + mt[wt] * 16 + quad * 4;
#pragma unroll
        for (int nt = 0; nt < 2; ++nt) {
            const int co = nt * 16 + m;
            const float tb = tv[co];
            unsigned short* ob = outN + (co >> 3) * (POOL ? 9216 : CGS1) + (co & 7);
            if (POOL) {
#pragma unroll
                for (int pi = 0; pi < 2; ++pi) {
                    int pe = pb + pi * 2;
                    int pr = pe / 30, rem = pe - pr * 30, w = rem >> 1;
                    float v0 = fmaxf(acc[nt][wt][pi * 2] + tb, 0.f);
                    float v1 = fmaxf(acc[nt][wt][pi * 2 + 1] + tb, 0.f);
                    ob[(pr * 16 + w) * 8] = f2h(fmaxf(v0, v1));
                }
            } else {
#pragma unroll
                for (int reg = 0; reg < 4; ++reg) {
                    int pr = pb + reg;
                    int f = pr / 15, w = pr - f * 15;
                    ob[((f + 1) * 17 + (w + 1)) * 8] = f2h(fmaxf(acc[nt][wt][reg] + tb, 0.f));
                }
            }
        }
    }
}

// ---------------------------------------------------------------------------
// conv5 MFMA: 32->64ch 3x3 VALID, in [4cg][72][16][8] -> out [8cg][70][16][8].
// ---------------------------------------------------------------------------
__global__ __launch_bounds__(256) void conv5m_k(
    const unsigned short* __restrict__ in, unsigned short* __restrict__ out,
    const unsigned short* __restrict__ frag, const float* __restrict__ tv)
{
    const int n = blockIdx.y;
    const int tid = threadIdx.x;
    const int wave = tid >> 6, lane = tid & 63;
    const int m = lane & 15, quad = lane >> 4;
    const unsigned short* inN = in + (size_t)n * REGH + quad * 9216;

    int mt[2], a0[2];
#pragma unroll
    for (int wt = 0; wt < 2; ++wt) {
        int t = blockIdx.x * 8 + wave * 2 + wt; if (t > 56) t = 56;
        mt[wt] = t;
        int p = t * 16 + m; if (p > 909) p = 909;
        int r = p / 13, w = p - r * 13;
        a0[wt] = (r * 16 + w) * 8;
    }

    v4f acc[4][2];
#pragma unroll
    for (int nt = 0; nt < 4; ++nt)
#pragma unroll
        for (int wt = 0; wt < 2; ++wt) acc[nt][wt] = (v4f){0.f,0.f,0.f,0.f};

#pragma unroll
    for (int khw = 0; khw < 9; ++khw) {
        const int shift = ((khw / 3) * 16 + (khw % 3)) * 8;
        v8h a[2];
#pragma unroll
        for (int wt = 0; wt < 2; ++wt)
            a[wt] = *(const v8h*)(inN + a0[wt] + shift);
#pragma unroll
        for (int nt = 0; nt < 4; ++nt) {
            v8h b = *(const v8h*)(frag + (khw * 4 + nt) * 512 + lane * 8);
#pragma unroll
            for (int wt = 0; wt < 2; ++wt)
                acc[nt][wt] = __builtin_amdgcn_mfma_f32_16x16x32_f16(a[wt], b, acc[nt][wt], 0, 0, 0);
        }
    }

    unsigned short* outN = out + (size_t)n * REGH;
#pragma unroll
    for (int wt = 0; wt < 2; ++wt) {
        const int pb = mt[wt] * 16 + quad * 4;
#pragma unroll
        for (int nt = 0; nt < 4; ++nt) {
            const int co = nt * 16 + m;
            const float tb = tv[co];
            unsigned short* ob = outN + (co >> 3) * 8960 + (co & 7);
#pragma unroll
            for (int reg = 0; reg < 4; ++reg) {
                int p = pb + reg;
                if (p < 910) {
                    int r = p / 13, w = p - r * 13;
                    ob[(r * 16 + w) * 8] = f2h(fmaxf(acc[nt][wt][reg] + tb, 0.f));
                }
            }
        }
    }
}

// ---------------------------------------------------------------------------
// conv6 MFMA (+fused pool) -> c6 [8cg][408 pos][8].
// ---------------------------------------------------------------------------
__global__ __launch_bounds__(256) void conv6m_k(
    const unsigned short* __restrict__ in, unsigned short* __restrict__ c6,
    const unsigned short* __restrict__ frag, const float* __restrict__ tv)
{
    const int n = blockIdx.y;
    const int tid = threadIdx.x;
    const int wave = tid >> 6, lane = tid & 63;
    const int m = lane & 15, quad = lane >> 4;
    const unsigned short* inN = in + (size_t)n * REGH;

    int mt[2], a0[2];
#pragma unroll
    for (int wt = 0; wt < 2; ++wt) {
        int t = blockIdx.x * 8 + wave * 2 + wt; if (t > 46) t = 46;
        mt[wt] = t;
        int p = t * 16 + m; if (p > 747) p = 747;
        int pr = p / 22, rem = p - pr * 22;
        int w = rem >> 1, r = pr * 2 + (rem & 1);
        a0[wt] = (r * 16 + w) * 8;
    }

    v4f acc[4][2];
#pragma unroll
    for (int nt = 0; nt < 4; ++nt)
#pragma unroll
        for (int wt = 0; wt < 2; ++wt) acc[nt][wt] = (v4f){0.f,0.f,0.f,0.f};

#pragma unroll
    for (int khw = 0; khw < 9; ++khw) {
        const int shift = ((khw / 3) * 16 + (khw % 3)) * 8;
#pragma unroll
        for (int half = 0; half < 2; ++half) {
            const unsigned short* ip = inN + (half * 4 + quad) * 8960 + shift;
            v8h a[2];
#pragma unroll
            for (int wt = 0; wt < 2; ++wt)
                a[wt] = *(const v8h*)(ip + a0[wt]);
#pragma unroll
            for (int nt = 0; nt < 4; ++nt) {
                v8h b = *(const v8h*)(frag + ((khw * 2 + half) * 4 + nt) * 512 + lane * 8);
#pragma unroll
                for (int wt = 0; wt < 2; ++wt)
                    acc[nt][wt] = __builtin_amdgcn_mfma_f32_16x16x32_f16(a[wt], b, acc[nt][wt], 0, 0, 0);
            }
        }
    }

    unsigned short* outN = c6 + (size_t)n * C6N;
#pragma unroll
    for (int wt = 0; wt < 2; ++wt) {
        const int pb = mt[wt] * 16 + quad * 4;
#pragma unroll
        for (int nt = 0; nt < 4; ++nt) {
            const int co = nt * 16 + m;
            const float tb = tv[co];
            unsigned short* ob = outN + (co >> 3) * 3264 + (co & 7);
#pragma unroll
            for (int pi = 0; pi < 2; ++pi) {
                int pe = pb + pi * 2;
                if (pe < 748) {
                    int pr = pe / 22, rem = pe - pr * 22, w = rem >> 1;
                    float v0 = fmaxf(acc[nt][wt][pi * 2] + tb, 0.f);
                    float v1 = fmaxf(acc[nt][wt][pi * 2 + 1] + tb, 0.f);
                    ob[(pr * 12 + w) * 8] = f2h(fmaxf(v0, v1));
                }
            }
        }
    }
}

// ---------------------------------------------------------------------------
// Conv7 MFMA GEMM (R9-proven config: 2 N-tiles x 5 M-tiles per wave, 48 VGPR,
// 42% occupancy; the R10 K x N split halved occupancy and lost 40%) + fused
// bias/relu/mean AND logits epilogue (pooled -> LDS -> 25x128 dot -> d_out).
// LDS: 443 quad stride / 13 row stride (bank fix, R9).
// ---------------------------------------------------------------------------
__global__ __launch_bounds__(256) void conv7mfma_k(
    const unsigned short* __restrict__ c6, float* __restrict__ outg,
    const unsigned short* __restrict__ frag7, const float* __restrict__ tv,
    const float* __restrict__ W8, const float* __restrict__ b8)
{
    __shared__ __align__(16) unsigned short sA[14176];  // 4 x 443 x 8
    __shared__ float sP[128];
    const int n = blockIdx.x;
    const int tid = threadIdx.x;
    const int wave = tid >> 6;
    const int lane = tid & 63;
    const int m = lane & 15;
    const int quad = lane >> 4;

    int pm[5];
#pragma unroll
    for (int mt = 0; mt < 5; ++mt) {
        int p = mt * 16 + m;
        if (p >= 69) p = 0;
        pm[mt] = (p / 3) * 13 + (p % 3);
    }

    v4f acc[2][5];
#pragma unroll
    for (int t = 0; t < 2; ++t)
#pragma unroll
        for (int mt = 0; mt < 5; ++mt)
            acc[t][mt] = (v4f){0.f, 0.f, 0.f, 0.f};

    for (int half = 0; half < 2; ++half) {
        __syncthreads();
        {
            const float4* src = (const float4*)(c6 + (size_t)n * C6N + half * 13056);
            float4* dst = (float4*)sA;
            for (int i = tid; i < 1632; i += 256) {
                int q = i / 408, pos = i - q * 408;
                int h = pos / 12, w = pos - h * 12;
                dst[q * 443 + h * 13 + w] = src[i];
            }
        }
        __syncthreads();
        for (int khw = 0; khw < 108; ++khw) {
            const int off = (khw / 9) * 13 + (khw % 9);
            v8h a[5];
#pragma unroll
            for (int mt = 0; mt < 5; ++mt)
                a[mt] = *(const v8h*)(sA + (quad * 443 + pm[mt] + off) * 8);
            const unsigned short* bp = frag7
                + ((size_t)(khw * 2 + half) * 8) * 512 + lane * 8;
#pragma unroll
            for (int t = 0; t < 2; ++t) {
                const int nt = wave + t * 4;
                v8h b = *(const v8h*)(bp + nt * 512);
#pragma unroll
                for (int mt = 0; mt < 5; ++mt)
                    acc[t][mt] = __builtin_amdgcn_mfma_f32_16x16x32_f16(
                        a[mt], b, acc[t][mt], 0, 0, 0);
            }
        }
    }

    // bias + relu + spatial mean -> sP[128]
    float s[2] = {0.f, 0.f};
#pragma unroll
    for (int t = 0; t < 2; ++t) {
        const float tb = tv[(wave + t * 4) * 16 + m];
#pragma unroll
        for (int mt = 0; mt < 5; ++mt) {
#pragma unroll
            for (int rr = 0; rr < 4; ++rr) {
                int p = mt * 16 + quad * 4 + rr;
                if (p < 69) s[t] += fmaxf(acc[t][mt][rr] + tb, 0.f);
            }
        }
    }
#pragma unroll
    for (int t = 0; t < 2; ++t) {
        s[t] += __shfl_xor(s[t], 16);
        s[t] += __shfl_xor(s[t], 32);
    }
    if (lane < 16) {
#pragma unroll
        for (int t = 0; t < 2; ++t)
            sP[(wave + t * 4) * 16 + lane] = s[t] * (1.f / 69.f);
    }
    __syncthreads();

    // logits epilogue: 25 threads, each one class (W8 row is L2/L3-resident)
    if (tid < 25) {
        const float* wp = W8 + tid * 128;
        float sc = b8[tid];
#pragma unroll
        for (int ci = 0; ci < 128; ci += 4) {
            float4 wv = *(const float4*)(wp + ci);
            sc = fmaf(wv.x, sP[ci],     sc);
            sc = fmaf(wv.y, sP[ci + 1], sc);
            sc = fmaf(wv.z, sP[ci + 2], sc);
            sc = fmaf(wv.w, sP[ci + 3], sc);
        }
        outg[(size_t)n * 25 + tid] = sc;
    }
}

// ---------------------------------------------------------------------------
extern "C" void kernel_launch(void* const* d_in, const int* in_sizes, int n_in,
                              void* d_out, int out_size, void* d_ws, size_t ws_size,
                              hipStream_t stream)
{
    const float* x = (const float*)d_in[0];
    const float* Wl[8]; const float* bl[8]; const float* gl[8];
    const float* bel[8]; const float* ml[8]; const float* vl[8];
    for (int i = 1; i <= 7; ++i) {
        int o = 2 + (i - 1) * 6;
        Wl[i]  = (const float*)d_in[o + 0];
        bl[i]  = (const float*)d_in[o + 1];
        gl[i]  = (const float*)d_in[o + 2];
        bel[i] = (const float*)d_in[o + 3];
        ml[i]  = (const float*)d_in[o + 4];
        vl[i]  = (const float*)d_in[o + 5];
    }
    const float* W8 = (const float*)d_in[44];
    const float* b8 = (const float*)d_in[45];
    float* ws = (float*)d_ws;

    // Workspace layout (float offsets); all 16B aligned.
    float* wr1 = ws + 0;        float* t1 = ws + 288;
    unsigned short* f2b = (unsigned short*)(ws + 320);
    float* t2 = ws + 4928;
    unsigned short* f3b = (unsigned short*)(ws + 4960);
    float* t3 = ws + 9568;
    unsigned short* f4b = (unsigned short*)(ws + 9600);
    float* t4 = ws + 14208;
    unsigned short* f5b = (unsigned short*)(ws + 14240);
    float* t5 = ws + 23456;
    unsigned short* f6b = (unsigned short*)(ws + 23520);
    float* t6 = ws + 41952;
    unsigned short* f7b = (unsigned short*)(ws + 42016);
    float* t7 = ws + 484384;
    const size_t WFL = 484512;

    // Persistent: c6 ([n][8][408][8] fp16).
    unsigned short* c6buf = (unsigned short*)(ws + WFL);
    const size_t C6FL = (size_t)1728 * C6N / 2;
    const size_t FIXED = WFL + C6FL;

    size_t avail_fl = ws_size / 4;
    size_t buf_halves = (avail_fl > FIXED) ? (avail_fl - FIXED) * 2 : 0;
    int Cs = (int)(buf_halves / (2 * (size_t)REGH));
    if (Cs < 1) Cs = 1;
    if (Cs > 1728) Cs = 1728;
    unsigned short* bufA = (unsigned short*)(ws + FIXED);
    unsigned short* bufB = bufA + (size_t)Cs * REGH;

    auto g1 = [](int t) { return (t + 255) / 256; };

    // Weight repacks (once per call)
    repack_k<<<g1(288), 256, 0, stream>>>(Wl[1], bl[1], gl[1], bel[1], ml[1], vl[1], wr1, t1, 1, 9, 32);
    repack_mfma_k<<<g1(9216),  256, 0, stream>>>(Wl[2], bl[2], gl[2], bel[2], ml[2], vl[2], f2b, t2, 32, 2, 1);
    repack_mfma_k<<<g1(9216),  256, 0, stream>>>(Wl[3], bl[3], gl[3], bel[3], ml[3], vl[3], f3b, t3, 32, 2, 1);
    repack_mfma_k<<<g1(9216),  256, 0, stream>>>(Wl[4], bl[4], gl[4], bel[4], ml[4], vl[4], f4b, t4, 32, 2, 1);
    repack_mfma_k<<<g1(18432), 256, 0, stream>>>(Wl[5], bl[5], gl[5], bel[5], ml[5], vl[5], f5b, t5, 32, 4, 1);
    repack_mfma_k<<<g1(36864), 256, 0, stream>>>(Wl[6], bl[6], gl[6], bel[6], ml[6], vl[6], f6b, t6, 64, 4, 2);
    repack7_k<<<g1(884736), 256, 0, stream>>>(Wl[7], bl[7], gl[7], bel[7], ml[7], vl[7], f7b, t7);

    // Ring zeros once per call (rings persist across chunks).
    zero_rings_k<<<g1(Cs * 2576), 256, 0, stream>>>(bufA, bufB, Cs);

    // Stage 1 (chunked): conv1..conv6 (all MFMA except conv1)
    for (int c0 = 0; c0 < 1728; c0 += Cs) {
        int cn = (1728 - c0 < Cs) ? (1728 - c0) : Cs;
        conv1_k<<<g1(cn * 2160), 256, 0, stream>>>(x, bufA, wr1, t1, c0, cn);
        conv234m_k<false><<<dim3(9, cn), 256, 0, stream>>>(bufA, bufB, f2b, t2);
        conv234m_k<false><<<dim3(9, cn), 256, 0, stream>>>(bufB, bufA, f3b, t3);
        conv234m_k<true ><<<dim3(9, cn), 256, 0, stream>>>(bufA, bufB, f4b, t4);
        conv5m_k<<<dim3(8, cn), 256, 0, stream>>>(bufB, bufA, f5b, t5);
        conv6m_k<<<dim3(6, cn), 256, 0, stream>>>(bufA, c6buf + (size_t)c0 * C6N, f6b, t6);
    }

    // Stage 2: conv7 MFMA + bias/relu/mean + logits, all samples, one launch.
    conv7mfma_k<<<1728, 256, 0, stream>>>(c6buf, (float*)d_out, f7b, t7, W8, b8);
}

// Round 12
// 1170.320 us; speedup vs baseline: 1.2575x; 1.1539x over previous
//
#include <hip/hip_runtime.h>
#include <hip/hip_bf16.h>
#include <hip/hip_fp16.h>

// Tight stage-1 activations. Per-sample slot = region A + region B (halves).
// A holds conv1/conv3 out [4cg][144][15][8]=69120 and conv5 out [8cg][70][16][8]=71680.
// B holds conv2 out (69120) and conv4-pool out [4cg][72][16][8]=36864.
#define TA 71680
#define TB 69120
#define SLOT 140800
// conv6 output halves per sample: [8 cgroups][408 pos][8 ci] fp16
#define C6N 26112

typedef _Float16 v8h __attribute__((ext_vector_type(8)));
typedef float v4f __attribute__((ext_vector_type(4)));
typedef unsigned short u16x8 __attribute__((ext_vector_type(8)));

__device__ inline float h2f(unsigned short u) {
    union { unsigned short s; _Float16 h; } v; v.s = u; return (float)v.h;
}
__device__ inline unsigned short f2h(float f) {
    union { unsigned short s; _Float16 h; } v; v.h = (_Float16)f; return v.s;
}

// ---------------------------------------------------------------------------
// conv1 weight repack (fp32): [co][1][kh][kw] -> [k][co], BN folded; emits t.
// ---------------------------------------------------------------------------
__global__ void repack_k(const float* __restrict__ W, const float* __restrict__ bb,
                         const float* __restrict__ gg, const float* __restrict__ be,
                         const float* __restrict__ mm, const float* __restrict__ vv,
                         float* __restrict__ wOut, float* __restrict__ tOut,
                         int CIN, int KHW, int COUT)
{
    int gid = blockIdx.x * 256 + threadIdx.x;
    if (gid < COUT) {
        float s = gg[gid] * rsqrtf(vv[gid] + 1e-5f);
        tOut[gid] = (bb[gid] - mm[gid]) * s + be[gid];
    }
    int tot = CIN * KHW * COUT;
    if (gid >= tot) return;
    int co = gid % COUT;
    int rest = gid / COUT;
    int k = rest % KHW;
    int ci = rest / KHW;
    float s = gg[co] * rsqrtf(vv[co] + 1e-5f);
    wOut[gid] = W[(co * CIN + ci) * KHW + k] * s;
}

// ---------------------------------------------------------------------------
// MFMA B-fragment repack for 3x3 layers (conv2..conv6), fp16.
// ---------------------------------------------------------------------------
__global__ void repack_mfma_k(const float* __restrict__ W, const float* __restrict__ bb,
                              const float* __restrict__ gg, const float* __restrict__ be,
                              const float* __restrict__ mm, const float* __restrict__ vv,
                              unsigned short* __restrict__ frag, float* __restrict__ tOut,
                              int CIN, int NT, int HALVES)
{
    int gid = blockIdx.x * 256 + threadIdx.x;
    int COUT = NT * 16;
    if (gid < COUT) {
        float s = gg[gid] * rsqrtf(vv[gid] + 1e-5f);
        tOut[gid] = (bb[gid] - mm[gid]) * s + be[gid];
    }
    int tot = 9 * HALVES * NT * 512;
    if (gid >= tot) return;
    int j    = gid & 7;
    int lane = (gid >> 3) & 63;
    int nt   = (gid >> 9) % NT;
    int rest = (gid >> 9) / NT;
    int half = rest % HALVES;
    int khw  = rest / HALVES;
    int ci   = half * 32 + (lane >> 4) * 8 + j;
    int co   = nt * 16 + (lane & 15);
    int kh   = khw / 3, kw = khw % 3;
    float s = gg[co] * rsqrtf(vv[co] + 1e-5f);
    frag[gid] = f2h(W[((co * CIN + ci) * 3 + kh) * 3 + kw] * s);
}

// ---------------------------------------------------------------------------
// Conv7 weight repack into MFMA B-fragment order (12x9 kernel), fp16.
// ---------------------------------------------------------------------------
__global__ void repack7_k(const float* __restrict__ W, const float* __restrict__ bb,
                          const float* __restrict__ gg, const float* __restrict__ be,
                          const float* __restrict__ mm, const float* __restrict__ vv,
                          unsigned short* __restrict__ frag, float* __restrict__ tOut)
{
    int gid = blockIdx.x * 256 + threadIdx.x;
    if (gid < 128) {
        float s = gg[gid] * rsqrtf(vv[gid] + 1e-5f);
        tOut[gid] = (bb[gid] - mm[gid]) * s + be[gid];
    }
    if (gid >= 884736) return;           // 108*2*8*64*8
    int j    = gid & 7;
    int lane = (gid >> 3) & 63;
    int nt   = (gid >> 9) & 7;
    int half = (gid >> 12) & 1;
    int khw  = gid >> 13;
    int co   = nt * 16 + (lane & 15);
    int ci   = half * 32 + (lane >> 4) * 8 + j;
    int kh   = khw / 9, kw = khw - kh * 9;
    float s = gg[co] * rsqrtf(vv[co] + 1e-5f);
    frag[gid] = f2h(W[((co * 64 + ci) * 12 + kh) * 9 + kw] * s);
}

// ---------------------------------------------------------------------------
// Conv1: 1 -> 32 channels, 3x3 SAME, tight channel-minor output [4cg][144][15][8].
// Two zero paddings on the window axis: conv SAME pad at cols -1/15 (always
// zero) and the T-padding (zero when t+c-7 outside [0,108)).
// ---------------------------------------------------------------------------
__global__ __launch_bounds__(256) void conv1_k(
    const float* __restrict__ x, unsigned short* __restrict__ out,
    const float* __restrict__ wr, const float* __restrict__ tv,
    int c0, int cn)
{
    int gid = blockIdx.x * 256 + threadIdx.x;
    if (gid >= cn * 2160) return;
    int nl = gid / 2160, p = gid - nl * 2160;
    int f = p / 15, w = p - f * 15;
    int n = c0 + nl;
    int b = n / 108, t = n - b * 108;

    float acc[32];
#pragma unroll
    for (int i = 0; i < 32; ++i) acc[i] = 0.f;

    for (int kh = 0; kh < 3; ++kh) {
        int ff = f + kh - 1;
        if (ff < 0 || ff >= 144) continue;
        for (int kw = 0; kw < 3; ++kw) {
            int c = w + kw - 1;
            if (c < 0 || c >= 15) continue;
            int tt = t + c - 7;
            if (tt < 0 || tt >= 108) continue;
            float xval = x[(b * 108 + tt) * 144 + ff];
            const float* wp = wr + (kh * 3 + kw) * 32;
#pragma unroll
            for (int q = 0; q < 8; ++q) {
                float4 wv = *(const float4*)(wp + q * 4);
                acc[q * 4 + 0] = fmaf(xval, wv.x, acc[q * 4 + 0]);
                acc[q * 4 + 1] = fmaf(xval, wv.y, acc[q * 4 + 1]);
                acc[q * 4 + 2] = fmaf(xval, wv.z, acc[q * 4 + 2]);
                acc[q * 4 + 3] = fmaf(xval, wv.w, acc[q * 4 + 3]);
            }
        }
    }
    unsigned short* ob = out + (size_t)nl * SLOT + (f * 15 + w) * 8;
#pragma unroll
    for (int cg = 0; cg < 4; ++cg) {
        u16x8 pk;
#pragma unroll
        for (int c = 0; c < 8; ++c)
            pk[c] = f2h(fmaxf(acc[cg * 8 + c] + tv[cg * 8 + c], 0.f));
        *(u16x8*)(ob + cg * 17280) = pk;
    }
}

// ---------------------------------------------------------------------------
// conv2/3/4 as MFMA implicit GEMM on TIGHT input [4cg][144][15][8].
// SAME-pad halos are zero-filled during the LDS slab staging (no global
// rings -> no cross-chunk ring-clobber hazard; R10/R11's hoisted ring-zero
// was a latent bug: conv4/conv5 tight outputs overwrote ring zeros).
// Slab: 4 quads x 18 rows x 17 cols, quad stride 307 (odd, bank-safe).
// ---------------------------------------------------------------------------
template<bool POOL>
__global__ __launch_bounds__(256) void conv234m_k(
    const unsigned short* __restrict__ in, unsigned short* __restrict__ out,
    const unsigned short* __restrict__ frag, const float* __restrict__ tv)
{
    __shared__ __align__(16) unsigned short sA[9824];  // 4 x 307 x 8
    const int band = blockIdx.x;
    const int n = blockIdx.y;
    const int tid = threadIdx.x;
    const int wave = tid >> 6, lane = tid & 63;
    const int m = lane & 15, quad = lane >> 4;

    // Stage slab with halo zero-fill: slab (q, r 0..17, c 0..16) <-
    // interior (band*16 + r - 1, c - 1), zero outside [0,144) x [0,15).
    {
        const float4* src = (const float4*)(in + (size_t)n * SLOT);
        float4* dst = (float4*)sA;
        for (int i = tid; i < 1224; i += 256) {
            int q = i / 306, pos = i - q * 306;
            int r = pos / 17, c = pos - r * 17;
            int ir = band * 16 + r - 1;
            int ic = c - 1;
            float4 v = {0.f, 0.f, 0.f, 0.f};
            if (ir >= 0 && ir < 144 && ic >= 0 && ic < 15)
                v = src[q * 2160 + ir * 15 + ic];
            dst[q * 307 + pos] = v;
        }
    }
    __syncthreads();

    int mt[4], la0[4];
#pragma unroll
    for (int wt = 0; wt < 4; ++wt) {
        int t = wave * 4 + wt; if (t > 14) t = 14;
        mt[wt] = t;
        int p = band * 240 + t * 16 + m;
        int r, w;
        if (POOL) { int pr = p / 30, rem = p - pr * 30; w = rem >> 1; r = pr * 2 + (rem & 1); }
        else      { r = p / 15; w = p - r * 15; }
        la0[wt] = ((r - band * 16) * 17 + w) * 8;   // slab coords (window top-left)
    }

    v4f acc[2][4];
#pragma unroll
    for (int nt = 0; nt < 2; ++nt)
#pragma unroll
        for (int wt = 0; wt < 4; ++wt) acc[nt][wt] = (v4f){0.f,0.f,0.f,0.f};

    const unsigned short* sQ = sA + quad * 307 * 8;
#pragma unroll
    for (int khw = 0; khw < 9; ++khw) {
        const int shift = ((khw / 3) * 17 + (khw % 3)) * 8;
        v8h a[4];
#pragma unroll
        for (int wt = 0; wt < 4; ++wt)
            a[wt] = *(const v8h*)(sQ + la0[wt] + shift);
#pragma unroll
        for (int nt = 0; nt < 2; ++nt) {
            v8h b = *(const v8h*)(frag + (khw * 2 + nt) * 512 + lane * 8);
#pragma unroll
            for (int wt = 0; wt < 4; ++wt)
                acc[nt][wt] = __builtin_amdgcn_mfma_f32_16x16x32_f16(a[wt], b, acc[nt][wt], 0, 0, 0);
        }
    }

    unsigned short* outN = out + (size_t)n * SLOT;
#pragma unroll
    for (int wt = 0; wt < 4; ++wt) {
        const int pb = band * 240 + mt[wt] * 16 + quad * 4;
#pragma unroll
        for (int nt = 0; nt < 2; ++nt) {
            const int co = nt * 16 + m;
            const float tb = tv[co];
            unsigned short* ob = outN + (co >> 3) * (POOL ? 9216 : 17280) + (co & 7);
            if (POOL) {
#pragma unroll
                for (int pi = 0; pi < 2; ++pi) {
                    int pe = pb + pi * 2;
                    int pr = pe / 30, rem = pe - pr * 30, w = rem >> 1;
                    float v0 = fmaxf(acc[nt][wt][pi * 2] + tb, 0.f);
                    float v1 = fmaxf(acc[nt][wt][pi * 2 + 1] + tb, 0.f);
                    ob[(pr * 16 + w) * 8] = f2h(fmaxf(v0, v1));
                }
            } else {
#pragma unroll
                for (int reg = 0; reg < 4; ++reg) {
                    int pr = pb + reg;
                    int f = pr / 15, w = pr - f * 15;
                    ob[(f * 15 + w) * 8] = f2h(fmaxf(acc[nt][wt][reg] + tb, 0.f));
                }
            }
        }
    }
}

// ---------------------------------------------------------------------------
// conv5 MFMA: 32->64ch 3x3 VALID, in [4cg][72][16][8] -> out [8cg][70][16][8].
// ---------------------------------------------------------------------------
__global__ __launch_bounds__(256) void conv5m_k(
    const unsigned short* __restrict__ in, unsigned short* __restrict__ out,
    const unsigned short* __restrict__ frag, const float* __restrict__ tv)
{
    const int n = blockIdx.y;
    const int tid = threadIdx.x;
    const int wave = tid >> 6, lane = tid & 63;
    const int m = lane & 15, quad = lane >> 4;
    const unsigned short* inN = in + (size_t)n * SLOT + quad * 9216;

    int mt[2], a0[2];
#pragma unroll
    for (int wt = 0; wt < 2; ++wt) {
        int t = blockIdx.x * 8 + wave * 2 + wt; if (t > 56) t = 56;
        mt[wt] = t;
        int p = t * 16 + m; if (p > 909) p = 909;
        int r = p / 13, w = p - r * 13;
        a0[wt] = (r * 16 + w) * 8;
    }

    v4f acc[4][2];
#pragma unroll
    for (int nt = 0; nt < 4; ++nt)
#pragma unroll
        for (int wt = 0; wt < 2; ++wt) acc[nt][wt] = (v4f){0.f,0.f,0.f,0.f};

#pragma unroll
    for (int khw = 0; khw < 9; ++khw) {
        const int shift = ((khw / 3) * 16 + (khw % 3)) * 8;
        v8h a[2];
#pragma unroll
        for (int wt = 0; wt < 2; ++wt)
            a[wt] = *(const v8h*)(inN + a0[wt] + shift);
#pragma unroll
        for (int nt = 0; nt < 4; ++nt) {
            v8h b = *(const v8h*)(frag + (khw * 4 + nt) * 512 + lane * 8);
#pragma unroll
            for (int wt = 0; wt < 2; ++wt)
                acc[nt][wt] = __builtin_amdgcn_mfma_f32_16x16x32_f16(a[wt], b, acc[nt][wt], 0, 0, 0);
        }
    }

    unsigned short* outN = out + (size_t)n * SLOT;
#pragma unroll
    for (int wt = 0; wt < 2; ++wt) {
        const int pb = mt[wt] * 16 + quad * 4;
#pragma unroll
        for (int nt = 0; nt < 4; ++nt) {
            const int co = nt * 16 + m;
            const float tb = tv[co];
            unsigned short* ob = outN + (co >> 3) * 8960 + (co & 7);
#pragma unroll
            for (int reg = 0; reg < 4; ++reg) {
                int p = pb + reg;
                if (p < 910) {
                    int r = p / 13, w = p - r * 13;
                    ob[(r * 16 + w) * 8] = f2h(fmaxf(acc[nt][wt][reg] + tb, 0.f));
                }
            }
        }
    }
}

// ---------------------------------------------------------------------------
// conv6 MFMA (+fused pool) -> c6 [8cg][408 pos][8].
// ---------------------------------------------------------------------------
__global__ __launch_bounds__(256) void conv6m_k(
    const unsigned short* __restrict__ in, unsigned short* __restrict__ c6,
    const unsigned short* __restrict__ frag, const float* __restrict__ tv)
{
    const int n = blockIdx.y;
    const int tid = threadIdx.x;
    const int wave = tid >> 6, lane = tid & 63;
    const int m = lane & 15, quad = lane >> 4;
    const unsigned short* inN = in + (size_t)n * SLOT;

    int mt[2], a0[2];
#pragma unroll
    for (int wt = 0; wt < 2; ++wt) {
        int t = blockIdx.x * 8 + wave * 2 + wt; if (t > 46) t = 46;
        mt[wt] = t;
        int p = t * 16 + m; if (p > 747) p = 747;
        int pr = p / 22, rem = p - pr * 22;
        int w = rem >> 1, r = pr * 2 + (rem & 1);
        a0[wt] = (r * 16 + w) * 8;
    }

    v4f acc[4][2];
#pragma unroll
    for (int nt = 0; nt < 4; ++nt)
#pragma unroll
        for (int wt = 0; wt < 2; ++wt) acc[nt][wt] = (v4f){0.f,0.f,0.f,0.f};

#pragma unroll
    for (int khw = 0; khw < 9; ++khw) {
        const int shift = ((khw / 3) * 16 + (khw % 3)) * 8;
#pragma unroll
        for (int half = 0; half < 2; ++half) {
            const unsigned short* ip = inN + (half * 4 + quad) * 8960 + shift;
            v8h a[2];
#pragma unroll
            for (int wt = 0; wt < 2; ++wt)
                a[wt] = *(const v8h*)(ip + a0[wt]);
#pragma unroll
            for (int nt = 0; nt < 4; ++nt) {
                v8h b = *(const v8h*)(frag + ((khw * 2 + half) * 4 + nt) * 512 + lane * 8);
#pragma unroll
                for (int wt = 0; wt < 2; ++wt)
                    acc[nt][wt] = __builtin_amdgcn_mfma_f32_16x16x32_f16(a[wt], b, acc[nt][wt], 0, 0, 0);
            }
        }
    }

    unsigned short* outN = c6 + (size_t)n * C6N;
#pragma unroll
    for (int wt = 0; wt < 2; ++wt) {
        const int pb = mt[wt] * 16 + quad * 4;
#pragma unroll
        for (int nt = 0; nt < 4; ++nt) {
            const int co = nt * 16 + m;
            const float tb = tv[co];
            unsigned short* ob = outN + (co >> 3) * 3264 + (co & 7);
#pragma unroll
            for (int pi = 0; pi < 2; ++pi) {
                int pe = pb + pi * 2;
                if (pe < 748) {
                    int pr = pe / 22, rem = pe - pr * 22, w = rem >> 1;
                    float v0 = fmaxf(acc[nt][wt][pi * 2] + tb, 0.f);
                    float v1 = fmaxf(acc[nt][wt][pi * 2 + 1] + tb, 0.f);
                    ob[(pr * 12 + w) * 8] = f2h(fmaxf(v0, v1));
                }
            }
        }
    }
}

// ---------------------------------------------------------------------------
// Conv7 MFMA GEMM — R9-proven config verbatim (2 N-tiles x 5 M-tiles/wave,
// 48 VGPR, 42% occupancy, MfmaUtil 60%; R10 K-split and R11 logits-fusion
// both regressed it). LDS: 443 quad stride / 13 row stride (bank fix).
// ---------------------------------------------------------------------------
__global__ __launch_bounds__(256) void conv7mfma_k(
    const unsigned short* __restrict__ c6, float* __restrict__ pooled,
    const unsigned short* __restrict__ frag7, const float* __restrict__ tv)
{
    __shared__ __align__(16) unsigned short sA[14176];  // 4 x 443 x 8
    const int n = blockIdx.x;
    const int tid = threadIdx.x;
    const int wave = tid >> 6;
    const int lane = tid & 63;
    const int m = lane & 15;
    const int quad = lane >> 4;

    int pm[5];
#pragma unroll
    for (int mt = 0; mt < 5; ++mt) {
        int p = mt * 16 + m;
        if (p >= 69) p = 0;
        pm[mt] = (p / 3) * 13 + (p % 3);
    }

    v4f acc[2][5];
#pragma unroll
    for (int t = 0; t < 2; ++t)
#pragma unroll
        for (int mt = 0; mt < 5; ++mt)
            acc[t][mt] = (v4f){0.f, 0.f, 0.f, 0.f};

    for (int half = 0; half < 2; ++half) {
        __syncthreads();
        {
            const float4* src = (const float4*)(c6 + (size_t)n * C6N + half * 13056);
            float4* dst = (float4*)sA;
            for (int i = tid; i < 1632; i += 256) {
                int q = i / 408, pos = i - q * 408;
                int h = pos / 12, w = pos - h * 12;
                dst[q * 443 + h * 13 + w] = src[i];
            }
        }
        __syncthreads();
        for (int khw = 0; khw < 108; ++khw) {
            const int off = (khw / 9) * 13 + (khw % 9);
            v8h a[5];
#pragma unroll
            for (int mt = 0; mt < 5; ++mt)
                a[mt] = *(const v8h*)(sA + (quad * 443 + pm[mt] + off) * 8);
            const unsigned short* bp = frag7
                + ((size_t)(khw * 2 + half) * 8) * 512 + lane * 8;
#pragma unroll
            for (int t = 0; t < 2; ++t) {
                const int nt = wave + t * 4;
                v8h b = *(const v8h*)(bp + nt * 512);
#pragma unroll
                for (int mt = 0; mt < 5; ++mt)
                    acc[t][mt] = __builtin_amdgcn_mfma_f32_16x16x32_f16(
                        a[mt], b, acc[t][mt], 0, 0, 0);
            }
        }
    }

    float s[2] = {0.f, 0.f};
#pragma unroll
    for (int t = 0; t < 2; ++t) {
        const float tb = tv[(wave + t * 4) * 16 + m];
#pragma unroll
        for (int mt = 0; mt < 5; ++mt) {
#pragma unroll
            for (int rr = 0; rr < 4; ++rr) {
                int p = mt * 16 + quad * 4 + rr;
                if (p < 69) s[t] += fmaxf(acc[t][mt][rr] + tb, 0.f);
            }
        }
    }
#pragma unroll
    for (int t = 0; t < 2; ++t) {
        s[t] += __shfl_xor(s[t], 16);
        s[t] += __shfl_xor(s[t], 32);
    }
    if (lane < 16) {
#pragma unroll
        for (int t = 0; t < 2; ++t)
            pooled[(size_t)n * 128 + (wave + t * 4) * 16 + lane] = s[t] * (1.f / 69.f);
    }
}

// ---------------------------------------------------------------------------
// logits = b8 + W8(25x128) . pooled
// ---------------------------------------------------------------------------
__global__ void logits_k(const float* __restrict__ pooled, const float* __restrict__ W8,
                         const float* __restrict__ b8, float* __restrict__ outg,
                         int total)
{
    int gid = blockIdx.x * 256 + threadIdx.x;
    if (gid >= total * 25) return;
    int nl = gid / 25, c = gid - nl * 25;
    const float* pp = pooled + (size_t)nl * 128;
    const float* wp = W8 + c * 128;
    float s = b8[c];
#pragma unroll
    for (int ci = 0; ci < 128; ci += 4) {
        float4 wv = *(const float4*)(wp + ci);
        float4 pv = *(const float4*)(pp + ci);
        s = fmaf(wv.x, pv.x, s);
        s = fmaf(wv.y, pv.y, s);
        s = fmaf(wv.z, pv.z, s);
        s = fmaf(wv.w, pv.w, s);
    }
    outg[(size_t)nl * 25 + c] = s;
}

// ---------------------------------------------------------------------------
extern "C" void kernel_launch(void* const* d_in, const int* in_sizes, int n_in,
                              void* d_out, int out_size, void* d_ws, size_t ws_size,
                              hipStream_t stream)
{
    const float* x = (const float*)d_in[0];
    const float* Wl[8]; const float* bl[8]; const float* gl[8];
    const float* bel[8]; const float* ml[8]; const float* vl[8];
    for (int i = 1; i <= 7; ++i) {
        int o = 2 + (i - 1) * 6;
        Wl[i]  = (const float*)d_in[o + 0];
        bl[i]  = (const float*)d_in[o + 1];
        gl[i]  = (const float*)d_in[o + 2];
        bel[i] = (const float*)d_in[o + 3];
        ml[i]  = (const float*)d_in[o + 4];
        vl[i]  = (const float*)d_in[o + 5];
    }
    const float* W8 = (const float*)d_in[44];
    const float* b8 = (const float*)d_in[45];
    float* ws = (float*)d_ws;

    // Workspace layout (float offsets); all 16B aligned.
    float* wr1 = ws + 0;        float* t1 = ws + 288;
    unsigned short* f2b = (unsigned short*)(ws + 320);
    float* t2 = ws + 4928;
    unsigned short* f3b = (unsigned short*)(ws + 4960);
    float* t3 = ws + 9568;
    unsigned short* f4b = (unsigned short*)(ws + 9600);
    float* t4 = ws + 14208;
    unsigned short* f5b = (unsigned short*)(ws + 14240);
    float* t5 = ws + 23456;
    unsigned short* f6b = (unsigned short*)(ws + 23520);
    float* t6 = ws + 41952;
    unsigned short* f7b = (unsigned short*)(ws + 42016);
    float* t7 = ws + 484384;
    const size_t WFL = 484512;

    // Persistent: c6 ([n][8][408][8] fp16) + pooled (fp32).
    unsigned short* c6buf = (unsigned short*)(ws + WFL);
    const size_t C6FL = (size_t)1728 * C6N / 2;
    float* pooled = ws + WFL + C6FL;
    const size_t FIXED = WFL + C6FL + (size_t)1728 * 128;

    size_t avail_fl = ws_size / 4;
    size_t buf_halves = (avail_fl > FIXED) ? (avail_fl - FIXED) * 2 : 0;
    int Cs = (int)(buf_halves / (size_t)SLOT);
    if (Cs < 1) Cs = 1;
    if (Cs > 1728) Cs = 1728;
    unsigned short* bufA = (unsigned short*)(ws + FIXED);   // region A (off 0)
    unsigned short* bufB = bufA + TA;                        // region B (off TA)

    auto g1 = [](int t) { return (t + 255) / 256; };

    // Weight repacks (once per call)
    repack_k<<<g1(288), 256, 0, stream>>>(Wl[1], bl[1], gl[1], bel[1], ml[1], vl[1], wr1, t1, 1, 9, 32);
    repack_mfma_k<<<g1(9216),  256, 0, stream>>>(Wl[2], bl[2], gl[2], bel[2], ml[2], vl[2], f2b, t2, 32, 2, 1);
    repack_mfma_k<<<g1(9216),  256, 0, stream>>>(Wl[3], bl[3], gl[3], bel[3], ml[3], vl[3], f3b, t3, 32, 2, 1);
    repack_mfma_k<<<g1(9216),  256, 0, stream>>>(Wl[4], bl[4], gl[4], bel[4], ml[4], vl[4], f4b, t4, 32, 2, 1);
    repack_mfma_k<<<g1(18432), 256, 0, stream>>>(Wl[5], bl[5], gl[5], bel[5], ml[5], vl[5], f5b, t5, 32, 4, 1);
    repack_mfma_k<<<g1(36864), 256, 0, stream>>>(Wl[6], bl[6], gl[6], bel[6], ml[6], vl[6], f6b, t6, 64, 4, 2);
    repack7_k<<<g1(884736), 256, 0, stream>>>(Wl[7], bl[7], gl[7], bel[7], ml[7], vl[7], f7b, t7);

    // Stage 1 (chunked, tight layouts, no rings):
    // conv1->A, conv2 A->B, conv3 B->A, conv4(pool) A->B, conv5 B->A, conv6 A->c6
    for (int c0 = 0; c0 < 1728; c0 += Cs) {
        int cn = (1728 - c0 < Cs) ? (1728 - c0) : Cs;
        conv1_k<<<g1(cn * 2160), 256, 0, stream>>>(x, bufA, wr1, t1, c0, cn);
        conv234m_k<false><<<dim3(9, cn), 256, 0, stream>>>(bufA, bufB, f2b, t2);
        conv234m_k<false><<<dim3(9, cn), 256, 0, stream>>>(bufB, bufA, f3b, t3);
        conv234m_k<true ><<<dim3(9, cn), 256, 0, stream>>>(bufA, bufB, f4b, t4);
        conv5m_k<<<dim3(8, cn), 256, 0, stream>>>(bufB, bufA, f5b, t5);
        conv6m_k<<<dim3(6, cn), 256, 0, stream>>>(bufA, c6buf + (size_t)c0 * C6N, f6b, t6);
    }

    // Stage 2: conv7 MFMA (+bias+relu+mean) over all samples, then logits.
    conv7mfma_k<<<1728, 256, 0, stream>>>(c6buf, pooled, f7b, t7);
    logits_k<<<g1(1728 * 25), 256, 0, stream>>>(pooled, W8, b8, (float*)d_out, 1728);
}

// Round 13
// 1133.744 us; speedup vs baseline: 1.2981x; 1.0323x over previous
//
#include <hip/hip_runtime.h>
#include <hip/hip_bf16.h>
#include <hip/hip_fp16.h>

// Tight stage-1 activations. Per-sample slot = region A + region B (halves).
// A: conv1 out [4cg][144][15][8]=69120, later conv5 out [8cg][70][16][8]=71680.
// B: conv4-pool out [4cg][72][16][8]=36864 (conv2/conv3 live in LDS only).
#define TA 71680
#define SLOT 108544
// conv6 output halves per sample: [8 cg][34 rows][11 cols][8 ci], row stride 11
#define C6N 23936

typedef _Float16 v8h __attribute__((ext_vector_type(8)));
typedef float v4f __attribute__((ext_vector_type(4)));
typedef unsigned short u16x8 __attribute__((ext_vector_type(8)));

__device__ inline float h2f(unsigned short u) {
    union { unsigned short s; _Float16 h; } v; v.s = u; return (float)v.h;
}
__device__ inline unsigned short f2h(float f) {
    union { unsigned short s; _Float16 h; } v; v.h = (_Float16)f; return v.s;
}

// ---------------------------------------------------------------------------
// conv1 weight repack (fp32): [co][1][kh][kw] -> [k][co], BN folded; emits t.
// ---------------------------------------------------------------------------
__global__ void repack_k(const float* __restrict__ W, const float* __restrict__ bb,
                         const float* __restrict__ gg, const float* __restrict__ be,
                         const float* __restrict__ mm, const float* __restrict__ vv,
                         float* __restrict__ wOut, float* __restrict__ tOut,
                         int CIN, int KHW, int COUT)
{
    int gid = blockIdx.x * 256 + threadIdx.x;
    if (gid < COUT) {
        float s = gg[gid] * rsqrtf(vv[gid] + 1e-5f);
        tOut[gid] = (bb[gid] - mm[gid]) * s + be[gid];
    }
    int tot = CIN * KHW * COUT;
    if (gid >= tot) return;
    int co = gid % COUT;
    int rest = gid / COUT;
    int k = rest % KHW;
    int ci = rest / KHW;
    float s = gg[co] * rsqrtf(vv[co] + 1e-5f);
    wOut[gid] = W[(co * CIN + ci) * KHW + k] * s;
}

// ---------------------------------------------------------------------------
// MFMA B-fragment repack for 3x3 layers (conv2..conv6), fp16.
// ---------------------------------------------------------------------------
__global__ void repack_mfma_k(const float* __restrict__ W, const float* __restrict__ bb,
                              const float* __restrict__ gg, const float* __restrict__ be,
                              const float* __restrict__ mm, const float* __restrict__ vv,
                              unsigned short* __restrict__ frag, float* __restrict__ tOut,
                              int CIN, int NT, int HALVES)
{
    int gid = blockIdx.x * 256 + threadIdx.x;
    int COUT = NT * 16;
    if (gid < COUT) {
        float s = gg[gid] * rsqrtf(vv[gid] + 1e-5f);
        tOut[gid] = (bb[gid] - mm[gid]) * s + be[gid];
    }
    int tot = 9 * HALVES * NT * 512;
    if (gid >= tot) return;
    int j    = gid & 7;
    int lane = (gid >> 3) & 63;
    int nt   = (gid >> 9) % NT;
    int rest = (gid >> 9) / NT;
    int half = rest % HALVES;
    int khw  = rest / HALVES;
    int ci   = half * 32 + (lane >> 4) * 8 + j;
    int co   = nt * 16 + (lane & 15);
    int kh   = khw / 3, kw = khw % 3;
    float s = gg[co] * rsqrtf(vv[co] + 1e-5f);
    frag[gid] = f2h(W[((co * CIN + ci) * 3 + kh) * 3 + kw] * s);
}

// ---------------------------------------------------------------------------
// Conv7 weight repack into MFMA B-fragment order (12x9 kernel), fp16.
// ---------------------------------------------------------------------------
__global__ void repack7_k(const float* __restrict__ W, const float* __restrict__ bb,
                          const float* __restrict__ gg, const float* __restrict__ be,
                          const float* __restrict__ mm, const float* __restrict__ vv,
                          unsigned short* __restrict__ frag, float* __restrict__ tOut)
{
    int gid = blockIdx.x * 256 + threadIdx.x;
    if (gid < 128) {
        float s = gg[gid] * rsqrtf(vv[gid] + 1e-5f);
        tOut[gid] = (bb[gid] - mm[gid]) * s + be[gid];
    }
    if (gid >= 884736) return;           // 108*2*8*64*8
    int j    = gid & 7;
    int lane = (gid >> 3) & 63;
    int nt   = (gid >> 9) & 7;
    int half = (gid >> 12) & 1;
    int khw  = gid >> 13;
    int co   = nt * 16 + (lane & 15);
    int ci   = half * 32 + (lane >> 4) * 8 + j;
    int kh   = khw / 9, kw = khw - kh * 9;
    float s = gg[co] * rsqrtf(vv[co] + 1e-5f);
    frag[gid] = f2h(W[((co * 64 + ci) * 12 + kh) * 9 + kw] * s);
}

// ---------------------------------------------------------------------------
// Conv1: 1 -> 32 channels, 3x3 SAME, tight channel-minor output [4cg][144][15][8].
// ---------------------------------------------------------------------------
__global__ __launch_bounds__(256) void conv1_k(
    const float* __restrict__ x, unsigned short* __restrict__ out,
    const float* __restrict__ wr, const float* __restrict__ tv,
    int c0, int cn)
{
    int gid = blockIdx.x * 256 + threadIdx.x;
    if (gid >= cn * 2160) return;
    int nl = gid / 2160, p = gid - nl * 2160;
    int f = p / 15, w = p - f * 15;
    int n = c0 + nl;
    int b = n / 108, t = n - b * 108;

    float acc[32];
#pragma unroll
    for (int i = 0; i < 32; ++i) acc[i] = 0.f;

    for (int kh = 0; kh < 3; ++kh) {
        int ff = f + kh - 1;
        if (ff < 0 || ff >= 144) continue;
        for (int kw = 0; kw < 3; ++kw) {
            int c = w + kw - 1;
            if (c < 0 || c >= 15) continue;
            int tt = t + c - 7;
            if (tt < 0 || tt >= 108) continue;
            float xval = x[(b * 108 + tt) * 144 + ff];
            const float* wp = wr + (kh * 3 + kw) * 32;
#pragma unroll
            for (int q = 0; q < 8; ++q) {
                float4 wv = *(const float4*)(wp + q * 4);
                acc[q * 4 + 0] = fmaf(xval, wv.x, acc[q * 4 + 0]);
                acc[q * 4 + 1] = fmaf(xval, wv.y, acc[q * 4 + 1]);
                acc[q * 4 + 2] = fmaf(xval, wv.z, acc[q * 4 + 2]);
                acc[q * 4 + 3] = fmaf(xval, wv.w, acc[q * 4 + 3]);
            }
        }
    }
    unsigned short* ob = out + (size_t)nl * SLOT + (f * 15 + w) * 8;
#pragma unroll
    for (int cg = 0; cg < 4; ++cg) {
        u16x8 pk;
#pragma unroll
        for (int c = 0; c < 8; ++c)
            pk[c] = f2h(fmaxf(acc[cg * 8 + c] + tv[cg * 8 + c], 0.f));
        *(u16x8*)(ob + cg * 17280) = pk;
    }
}

// ---------------------------------------------------------------------------
// FUSED conv2+conv3+conv4(+pool), MFMA implicit GEMM, per (band, sample).
// Stages conv1-out slab (22 rows + halos) once; conv2 (20 rows, 25% redundant)
// and conv3 (18 rows) live only in LDS (conv3 slab aliases the dead conv1
// slab); conv4+pool writes global B. Saves 4 global round-trips and 2
// dispatches per chunk vs the separate kernels (stage-1 was traffic/dispatch
// bound: per-dispatch MFMA work ~1us vs ~30us measured).
// LDS chunks (16B units): s1 = 4 quads x 375 (22r x 17c, stride odd),
// s2 at 1500 = 4 x 341 (20r x 17c), s3 aliases s1 = 4 x 307 (18r x 17c).
// ---------------------------------------------------------------------------
__global__ __launch_bounds__(256) void conv234f_k(
    const unsigned short* __restrict__ in, unsigned short* __restrict__ out,
    const unsigned short* __restrict__ f2, const unsigned short* __restrict__ f3,
    const unsigned short* __restrict__ f4, const float* __restrict__ t2,
    const float* __restrict__ t3, const float* __restrict__ t4)
{
    __shared__ __align__(16) unsigned short sm[22912];   // 45824 B
    const int band = blockIdx.x;
    const int n = blockIdx.y;
    const int tid = threadIdx.x;
    const int wave = tid >> 6, lane = tid & 63;
    const int m = lane & 15, quad = lane >> 4;

    // Stage conv1 slab (+ zero s2 halo cols).
    {
        const float4* src = (const float4*)(in + (size_t)n * SLOT);
        float4* dst = (float4*)sm;
        const float4 z = {0.f, 0.f, 0.f, 0.f};
        for (int i = tid; i < 1656; i += 256) {
            if (i < 1496) {
                int q = i / 374, pos = i - q * 374;
                int r = pos / 17, c = pos - r * 17;
                int gr = band * 16 + r - 3;
                int gc = c - 1;
                float4 v = z;
                if (gr >= 0 && gr < 144 && gc >= 0 && gc < 15)
                    v = src[q * 2160 + gr * 15 + gc];
                dst[q * 375 + pos + (r > 0 ? r : 0) * 0 + r * 0 + 0 + (pos - pos)] = v;
                // (dst index = q*375 + r*17 + c = q*375 + pos)
                dst[q * 375 + pos] = v;
            } else {
                int j = i - 1496;                 // s2 halo: 4q x 20r x 2cols
                int q = j / 40, jj = j - q * 40;
                int rr = jj >> 1, c2 = (jj & 1) * 16;
                dst[1500 + q * 341 + rr * 17 + c2] = z;
            }
        }
    }
    __syncthreads();

    v4f acc[2][5];
    int mt[5], la[5];

    // ---------------- conv2: 20 rows x 15 cols = 300 pos, 19 tiles ----------
#pragma unroll
    for (int wt = 0; wt < 5; ++wt) {
        int t = wave * 5 + wt; if (t > 18) t = 18;
        mt[wt] = t;
        int p = t * 16 + m; if (p >= 300) p = 299;
        int r = p / 15, c = p - r * 15;
        la[wt] = r * 17 + c;
    }
#pragma unroll
    for (int nt = 0; nt < 2; ++nt)
#pragma unroll
        for (int wt = 0; wt < 5; ++wt) acc[nt][wt] = (v4f){0.f,0.f,0.f,0.f};
#pragma unroll
    for (int khw = 0; khw < 9; ++khw) {
        const int sh = (khw / 3) * 17 + (khw % 3);
        v8h a[5];
#pragma unroll
        for (int wt = 0; wt < 5; ++wt)
            a[wt] = *(const v8h*)(sm + quad * 3000 + (la[wt] + sh) * 8);
#pragma unroll
        for (int nt = 0; nt < 2; ++nt) {
            v8h b = *(const v8h*)(f2 + (khw * 2 + nt) * 512 + lane * 8);
#pragma unroll
            for (int wt = 0; wt < 5; ++wt)
                acc[nt][wt] = __builtin_amdgcn_mfma_f32_16x16x32_f16(a[wt], b, acc[nt][wt], 0, 0, 0);
        }
    }
#pragma unroll
    for (int wt = 0; wt < 5; ++wt) {
        const int pb = mt[wt] * 16 + quad * 4;
#pragma unroll
        for (int nt = 0; nt < 2; ++nt) {
            const int co = nt * 16 + m;
            const float tb = t2[co];
            unsigned short* ob = sm + 12000 + (co >> 3) * 2728 + (co & 7);
#pragma unroll
            for (int reg = 0; reg < 4; ++reg) {
                int p = pb + reg;
                if (p < 300) {
                    int r = p / 15, c = p - r * 15;
                    ob[(r * 17 + c + 1) * 8] = f2h(fmaxf(acc[nt][wt][reg] + tb, 0.f));
                }
            }
        }
    }
    __syncthreads();

    // zero s3 halo cols (s3 aliases dead conv1 slab)
    if (tid < 144) {
        int q = tid / 36, jj = tid - q * 36;
        int rr = jj >> 1, c2 = (jj & 1) * 16;
        *(float4*)((float4*)sm + q * 307 + rr * 17 + c2) = (float4){0.f,0.f,0.f,0.f};
    }

    // ---------------- conv3: 18 rows x 15 cols = 270 pos, 17 tiles ----------
#pragma unroll
    for (int wt = 0; wt < 5; ++wt) {
        int t = wave * 5 + wt; if (t > 16) t = 16;
        mt[wt] = t;
        int p = t * 16 + m; if (p >= 270) p = 269;
        int r = p / 15, c = p - r * 15;
        la[wt] = r * 17 + c;
    }
#pragma unroll
    for (int nt = 0; nt < 2; ++nt)
#pragma unroll
        for (int wt = 0; wt < 5; ++wt) acc[nt][wt] = (v4f){0.f,0.f,0.f,0.f};
#pragma unroll
    for (int khw = 0; khw < 9; ++khw) {
        const int sh = (khw / 3) * 17 + (khw % 3);
        v8h a[5];
#pragma unroll
        for (int wt = 0; wt < 5; ++wt)
            a[wt] = *(const v8h*)(sm + 12000 + quad * 2728 + (la[wt] + sh) * 8);
#pragma unroll
        for (int nt = 0; nt < 2; ++nt) {
            v8h b = *(const v8h*)(f3 + (khw * 2 + nt) * 512 + lane * 8);
#pragma unroll
            for (int wt = 0; wt < 5; ++wt)
                acc[nt][wt] = __builtin_amdgcn_mfma_f32_16x16x32_f16(a[wt], b, acc[nt][wt], 0, 0, 0);
        }
    }
#pragma unroll
    for (int wt = 0; wt < 5; ++wt) {
        const int pb = mt[wt] * 16 + quad * 4;
#pragma unroll
        for (int nt = 0; nt < 2; ++nt) {
            const int co = nt * 16 + m;
            const float tb = t3[co];
            unsigned short* ob = sm + (co >> 3) * 2456 + (co & 7);
#pragma unroll
            for (int reg = 0; reg < 4; ++reg) {
                int p = pb + reg;
                if (p < 270) {
                    int r = p / 15, c = p - r * 15;
                    ob[(r * 17 + c + 1) * 8] = f2h(fmaxf(acc[nt][wt][reg] + tb, 0.f));
                }
            }
        }
    }
    __syncthreads();

    // ---------------- conv4 + pool: 240 pos (pr,w,s ordered), 15 tiles ------
    int mt4[4], la4[4];
#pragma unroll
    for (int wt = 0; wt < 4; ++wt) {
        int t = wave * 4 + wt; if (t > 14) t = 14;
        mt4[wt] = t;
        int p = t * 16 + m;
        int pr = p / 30, rem = p - pr * 30;
        int w = rem >> 1, r4 = pr * 2 + (rem & 1);
        la4[wt] = r4 * 17 + w;
    }
    v4f acc4[2][4];
#pragma unroll
    for (int nt = 0; nt < 2; ++nt)
#pragma unroll
        for (int wt = 0; wt < 4; ++wt) acc4[nt][wt] = (v4f){0.f,0.f,0.f,0.f};
#pragma unroll
    for (int khw = 0; khw < 9; ++khw) {
        const int sh = (khw / 3) * 17 + (khw % 3);
        v8h a[4];
#pragma unroll
        for (int wt = 0; wt < 4; ++wt)
            a[wt] = *(const v8h*)(sm + quad * 2456 + (la4[wt] + sh) * 8);
#pragma unroll
        for (int nt = 0; nt < 2; ++nt) {
            v8h b = *(const v8h*)(f4 + (khw * 2 + nt) * 512 + lane * 8);
#pragma unroll
            for (int wt = 0; wt < 4; ++wt)
                acc4[nt][wt] = __builtin_amdgcn_mfma_f32_16x16x32_f16(a[wt], b, acc4[nt][wt], 0, 0, 0);
        }
    }
    unsigned short* outN = out + (size_t)n * SLOT;
#pragma unroll
    for (int wt = 0; wt < 4; ++wt) {
        const int pb = band * 240 + mt4[wt] * 16 + quad * 4;
#pragma unroll
        for (int nt = 0; nt < 2; ++nt) {
            const int co = nt * 16 + m;
            const float tb = t4[co];
            unsigned short* ob = outN + (co >> 3) * 9216 + (co & 7);
#pragma unroll
            for (int pi = 0; pi < 2; ++pi) {
                int pe = pb + pi * 2;
                int pr = pe / 30, rem = pe - pr * 30, w = rem >> 1;
                float v0 = fmaxf(acc4[nt][wt][pi * 2] + tb, 0.f);
                float v1 = fmaxf(acc4[nt][wt][pi * 2 + 1] + tb, 0.f);
                ob[(pr * 16 + w) * 8] = f2h(fmaxf(v0, v1));
            }
        }
    }
}

// ---------------------------------------------------------------------------
// conv5 MFMA: 32->64ch 3x3 VALID, in [4cg][72][16][8] -> out [8cg][70][16][8].
// ---------------------------------------------------------------------------
__global__ __launch_bounds__(256) void conv5m_k(
    const unsigned short* __restrict__ in, unsigned short* __restrict__ out,
    const unsigned short* __restrict__ frag, const float* __restrict__ tv)
{
    const int n = blockIdx.y;
    const int tid = threadIdx.x;
    const int wave = tid >> 6, lane = tid & 63;
    const int m = lane & 15, quad = lane >> 4;
    const unsigned short* inN = in + (size_t)n * SLOT + quad * 9216;

    int mt[2], a0[2];
#pragma unroll
    for (int wt = 0; wt < 2; ++wt) {
        int t = blockIdx.x * 8 + wave * 2 + wt; if (t > 56) t = 56;
        mt[wt] = t;
        int p = t * 16 + m; if (p > 909) p = 909;
        int r = p / 13, w = p - r * 13;
        a0[wt] = (r * 16 + w) * 8;
    }

    v4f acc[4][2];
#pragma unroll
    for (int nt = 0; nt < 4; ++nt)
#pragma unroll
        for (int wt = 0; wt < 2; ++wt) acc[nt][wt] = (v4f){0.f,0.f,0.f,0.f};

#pragma unroll
    for (int khw = 0; khw < 9; ++khw) {
        const int shift = ((khw / 3) * 16 + (khw % 3)) * 8;
        v8h a[2];
#pragma unroll
        for (int wt = 0; wt < 2; ++wt)
            a[wt] = *(const v8h*)(inN + a0[wt] + shift);
#pragma unroll
        for (int nt = 0; nt < 4; ++nt) {
            v8h b = *(const v8h*)(frag + (khw * 4 + nt) * 512 + lane * 8);
#pragma unroll
            for (int wt = 0; wt < 2; ++wt)
                acc[nt][wt] = __builtin_amdgcn_mfma_f32_16x16x32_f16(a[wt], b, acc[nt][wt], 0, 0, 0);
        }
    }

    unsigned short* outN = out + (size_t)n * SLOT;
#pragma unroll
    for (int wt = 0; wt < 2; ++wt) {
        const int pb = mt[wt] * 16 + quad * 4;
#pragma unroll
        for (int nt = 0; nt < 4; ++nt) {
            const int co = nt * 16 + m;
            const float tb = tv[co];
            unsigned short* ob = outN + (co >> 3) * 8960 + (co & 7);
#pragma unroll
            for (int reg = 0; reg < 4; ++reg) {
                int p = pb + reg;
                if (p < 910) {
                    int r = p / 13, w = p - r * 13;
                    ob[(r * 16 + w) * 8] = f2h(fmaxf(acc[nt][wt][reg] + tb, 0.f));
                }
            }
        }
    }
}

// ---------------------------------------------------------------------------
// conv6 MFMA (+fused pool) -> c6 [8cg][34r][11c][8], row stride 11.
// ---------------------------------------------------------------------------
__global__ __launch_bounds__(256) void conv6m_k(
    const unsigned short* __restrict__ in, unsigned short* __restrict__ c6,
    const unsigned short* __restrict__ frag, const float* __restrict__ tv)
{
    const int n = blockIdx.y;
    const int tid = threadIdx.x;
    const int wave = tid >> 6, lane = tid & 63;
    const int m = lane & 15, quad = lane >> 4;
    const unsigned short* inN = in + (size_t)n * SLOT;

    int mt[2], a0[2];
#pragma unroll
    for (int wt = 0; wt < 2; ++wt) {
        int t = blockIdx.x * 8 + wave * 2 + wt; if (t > 46) t = 46;
        mt[wt] = t;
        int p = t * 16 + m; if (p > 747) p = 747;
        int pr = p / 22, rem = p - pr * 22;
        int w = rem >> 1, r = pr * 2 + (rem & 1);
        a0[wt] = (r * 16 + w) * 8;
    }

    v4f acc[4][2];
#pragma unroll
    for (int nt = 0; nt < 4; ++nt)
#pragma unroll
        for (int wt = 0; wt < 2; ++wt) acc[nt][wt] = (v4f){0.f,0.f,0.f,0.f};

#pragma unroll
    for (int khw = 0; khw < 9; ++khw) {
        const int shift = ((khw / 3) * 16 + (khw % 3)) * 8;
#pragma unroll
        for (int half = 0; half < 2; ++half) {
            const unsigned short* ip = inN + (half * 4 + quad) * 8960 + shift;
            v8h a[2];
#pragma unroll
            for (int wt = 0; wt < 2; ++wt)
                a[wt] = *(const v8h*)(ip + a0[wt]);
#pragma unroll
            for (int nt = 0; nt < 4; ++nt) {
                v8h b = *(const v8h*)(frag + ((khw * 2 + half) * 4 + nt) * 512 + lane * 8);
#pragma unroll
                for (int wt = 0; wt < 2; ++wt)
                    acc[nt][wt] = __builtin_amdgcn_mfma_f32_16x16x32_f16(a[wt], b, acc[nt][wt], 0, 0, 0);
            }
        }
    }

    unsigned short* outN = c6 + (size_t)n * C6N;
#pragma unroll
    for (int wt = 0; wt < 2; ++wt) {
        const int pb = mt[wt] * 16 + quad * 4;
#pragma unroll
        for (int nt = 0; nt < 4; ++nt) {
            const int co = nt * 16 + m;
            const float tb = tv[co];
            unsigned short* ob = outN + (co >> 3) * 2992 + (co & 7);
#pragma unroll
            for (int pi = 0; pi < 2; ++pi) {
                int pe = pb + pi * 2;
                if (pe < 748) {
                    int pr = pe / 22, rem = pe - pr * 22, w = rem >> 1;
                    float v0 = fmaxf(acc[nt][wt][pi * 2] + tb, 0.f);
                    float v1 = fmaxf(acc[nt][wt][pi * 2 + 1] + tb, 0.f);
                    ob[(pr * 11 + w) * 8] = f2h(fmaxf(v0, v1));
                }
            }
        }
    }
}

// ---------------------------------------------------------------------------
// Conv7 MFMA GEMM (R9/R12-proven config). LDS layout: row stride 11 (=3 mod 8
// -> h*11+w runs through consecutive residues for consecutive p: exactly
// uniform 2-way = free), quad stride 374 chunks; staging is a straight
// contiguous copy (c6 now stored row-stride-11).
// ---------------------------------------------------------------------------
__global__ __launch_bounds__(256) void conv7mfma_k(
    const unsigned short* __restrict__ c6, float* __restrict__ pooled,
    const unsigned short* __restrict__ frag7, const float* __restrict__ tv)
{
    __shared__ __align__(16) unsigned short sA[11968];  // 4 x 374 x 8
    const int n = blockIdx.x;
    const int tid = threadIdx.x;
    const int wave = tid >> 6;
    const int lane = tid & 63;
    const int m = lane & 15;
    const int quad = lane >> 4;

    int pm[5];
#pragma unroll
    for (int mt = 0; mt < 5; ++mt) {
        int p = mt * 16 + m;
        if (p >= 69) p = 0;
        pm[mt] = (p / 3) * 11 + (p % 3);
    }

    v4f acc[2][5];
#pragma unroll
    for (int t = 0; t < 2; ++t)
#pragma unroll
        for (int mt = 0; mt < 5; ++mt)
            acc[t][mt] = (v4f){0.f, 0.f, 0.f, 0.f};

    for (int half = 0; half < 2; ++half) {
        __syncthreads();
        {
            const float4* src = (const float4*)(c6 + (size_t)n * C6N + half * 11968);
            float4* dst = (float4*)sA;
            for (int i = tid; i < 1496; i += 256) dst[i] = src[i];
        }
        __syncthreads();
        for (int khw = 0; khw < 108; ++khw) {
            const int off = (khw / 9) * 11 + (khw % 9);
            v8h a[5];
#pragma unroll
            for (int mt = 0; mt < 5; ++mt)
                a[mt] = *(const v8h*)(sA + quad * 2992 + (pm[mt] + off) * 8);
            const unsigned short* bp = frag7
                + ((size_t)(khw * 2 + half) * 8) * 512 + lane * 8;
#pragma unroll
            for (int t = 0; t < 2; ++t) {
                const int nt = wave + t * 4;
                v8h b = *(const v8h*)(bp + nt * 512);
#pragma unroll
                for (int mt = 0; mt < 5; ++mt)
                    acc[t][mt] = __builtin_amdgcn_mfma_f32_16x16x32_f16(
                        a[mt], b, acc[t][mt], 0, 0, 0);
            }
        }
    }

    float s[2] = {0.f, 0.f};
#pragma unroll
    for (int t = 0; t < 2; ++t) {
        const float tb = tv[(wave + t * 4) * 16 + m];
#pragma unroll
        for (int mt = 0; mt < 5; ++mt) {
#pragma unroll
            for (int rr = 0; rr < 4; ++rr) {
                int p = mt * 16 + quad * 4 + rr;
                if (p < 69) s[t] += fmaxf(acc[t][mt][rr] + tb, 0.f);
            }
        }
    }
#pragma unroll
    for (int t = 0; t < 2; ++t) {
        s[t] += __shfl_xor(s[t], 16);
        s[t] += __shfl_xor(s[t], 32);
    }
    if (lane < 16) {
#pragma unroll
        for (int t = 0; t < 2; ++t)
            pooled[(size_t)n * 128 + (wave + t * 4) * 16 + lane] = s[t] * (1.f / 69.f);
    }
}

// ---------------------------------------------------------------------------
// logits = b8 + W8(25x128) . pooled
// ---------------------------------------------------------------------------
__global__ void logits_k(const float* __restrict__ pooled, const float* __restrict__ W8,
                         const float* __restrict__ b8, float* __restrict__ outg,
                         int total)
{
    int gid = blockIdx.x * 256 + threadIdx.x;
    if (gid >= total * 25) return;
    int nl = gid / 25, c = gid - nl * 25;
    const float* pp = pooled + (size_t)nl * 128;
    const float* wp = W8 + c * 128;
    float s = b8[c];
#pragma unroll
    for (int ci = 0; ci < 128; ci += 4) {
        float4 wv = *(const float4*)(wp + ci);
        float4 pv = *(const float4*)(pp + ci);
        s = fmaf(wv.x, pv.x, s);
        s = fmaf(wv.y, pv.y, s);
        s = fmaf(wv.z, pv.z, s);
        s = fmaf(wv.w, pv.w, s);
    }
    outg[(size_t)nl * 25 + c] = s;
}

// ---------------------------------------------------------------------------
extern "C" void kernel_launch(void* const* d_in, const int* in_sizes, int n_in,
                              void* d_out, int out_size, void* d_ws, size_t ws_size,
                              hipStream_t stream)
{
    const float* x = (const float*)d_in[0];
    const float* Wl[8]; const float* bl[8]; const float* gl[8];
    const float* bel[8]; const float* ml[8]; const float* vl[8];
    for (int i = 1; i <= 7; ++i) {
        int o = 2 + (i - 1) * 6;
        Wl[i]  = (const float*)d_in[o + 0];
        bl[i]  = (const float*)d_in[o + 1];
        gl[i]  = (const float*)d_in[o + 2];
        bel[i] = (const float*)d_in[o + 3];
        ml[i]  = (const float*)d_in[o + 4];
        vl[i]  = (const float*)d_in[o + 5];
    }
    const float* W8 = (const float*)d_in[44];
    const float* b8 = (const float*)d_in[45];
    float* ws = (float*)d_ws;

    // Workspace layout (float offsets); all 16B aligned.
    float* wr1 = ws + 0;        float* t1 = ws + 288;
    unsigned short* f2b = (unsigned short*)(ws + 320);
    float* t2 = ws + 4928;
    unsigned short* f3b = (unsigned short*)(ws + 4960);
    float* t3 = ws + 9568;
    unsigned short* f4b = (unsigned short*)(ws + 9600);
    float* t4 = ws + 14208;
    unsigned short* f5b = (unsigned short*)(ws + 14240);
    float* t5 = ws + 23456;
    unsigned short* f6b = (unsigned short*)(ws + 23520);
    float* t6 = ws + 41952;
    unsigned short* f7b = (unsigned short*)(ws + 42016);
    float* t7 = ws + 484384;
    const size_t WFL = 484512;

    // Persistent: c6 ([n][8][374][8] fp16, row stride 11) + pooled (fp32).
    unsigned short* c6buf = (unsigned short*)(ws + WFL);
    const size_t C6FL = (size_t)1728 * C6N / 2;
    float* pooled = ws + WFL + C6FL;
    const size_t FIXED = WFL + C6FL + (size_t)1728 * 128;

    size_t avail_fl = ws_size / 4;
    size_t buf_halves = (avail_fl > FIXED) ? (avail_fl - FIXED) * 2 : 0;
    int Cs = (int)(buf_halves / (size_t)SLOT);
    if (Cs < 1) Cs = 1;
    if (Cs > 1728) Cs = 1728;
    unsigned short* bufA = (unsigned short*)(ws + FIXED);   // region A (off 0)
    unsigned short* bufB = bufA + TA;                        // region B (off TA)

    auto g1 = [](int t) { return (t + 255) / 256; };

    // Weight repacks (once per call)
    repack_k<<<g1(288), 256, 0, stream>>>(Wl[1], bl[1], gl[1], bel[1], ml[1], vl[1], wr1, t1, 1, 9, 32);
    repack_mfma_k<<<g1(9216),  256, 0, stream>>>(Wl[2], bl[2], gl[2], bel[2], ml[2], vl[2], f2b, t2, 32, 2, 1);
    repack_mfma_k<<<g1(9216),  256, 0, stream>>>(Wl[3], bl[3], gl[3], bel[3], ml[3], vl[3], f3b, t3, 32, 2, 1);
    repack_mfma_k<<<g1(9216),  256, 0, stream>>>(Wl[4], bl[4], gl[4], bel[4], ml[4], vl[4], f4b, t4, 32, 2, 1);
    repack_mfma_k<<<g1(18432), 256, 0, stream>>>(Wl[5], bl[5], gl[5], bel[5], ml[5], vl[5], f5b, t5, 32, 4, 1);
    repack_mfma_k<<<g1(36864), 256, 0, stream>>>(Wl[6], bl[6], gl[6], bel[6], ml[6], vl[6], f6b, t6, 64, 4, 2);
    repack7_k<<<g1(884736), 256, 0, stream>>>(Wl[7], bl[7], gl[7], bel[7], ml[7], vl[7], f7b, t7);

    // Stage 1 (chunked, tight layouts):
    // conv1->A, fused conv2/3/4 A->B, conv5 B->A, conv6 A->c6
    for (int c0 = 0; c0 < 1728; c0 += Cs) {
        int cn = (1728 - c0 < Cs) ? (1728 - c0) : Cs;
        conv1_k<<<g1(cn * 2160), 256, 0, stream>>>(x, bufA, wr1, t1, c0, cn);
        conv234f_k<<<dim3(9, cn), 256, 0, stream>>>(bufA, bufB, f2b, f3b, f4b, t2, t3, t4);
        conv5m_k<<<dim3(8, cn), 256, 0, stream>>>(bufB, bufA, f5b, t5);
        conv6m_k<<<dim3(6, cn), 256, 0, stream>>>(bufA, c6buf + (size_t)c0 * C6N, f6b, t6);
    }

    // Stage 2: conv7 MFMA (+bias+relu+mean) over all samples, then logits.
    conv7mfma_k<<<1728, 256, 0, stream>>>(c6buf, pooled, f7b, t7);
    logits_k<<<g1(1728 * 25), 256, 0, stream>>>(pooled, W8, b8, (float*)d_out, 1728);
}

// Round 14
// 1129.856 us; speedup vs baseline: 1.3026x; 1.0034x over previous
//
#include <hip/hip_runtime.h>
#include <hip/hip_bf16.h>
#include <hip/hip_fp16.h>

// Tight stage-1 activations. Per-sample slot = region A + region B (halves).
// A: conv5 out [8cg][70][16][8]=71680. B: conv4-pool out [4cg][72][16][8]=36864.
// conv1/conv2/conv3 outs live in LDS only (fused band kernel).
#define TA 71680
#define SLOT 108544
// conv6 output halves per sample: [8 cg][34 rows][11 cols][8 ci], row stride 11
#define C6N 23936

typedef _Float16 v8h __attribute__((ext_vector_type(8)));
typedef float v4f __attribute__((ext_vector_type(4)));
typedef unsigned short u16x8 __attribute__((ext_vector_type(8)));

__device__ inline float h2f(unsigned short u) {
    union { unsigned short s; _Float16 h; } v; v.s = u; return (float)v.h;
}
__device__ inline unsigned short f2h(float f) {
    union { unsigned short s; _Float16 h; } v; v.h = (_Float16)f; return v.s;
}

// ---------------------------------------------------------------------------
// conv1 weight repack (fp32): [co][1][kh][kw] -> [k][co], BN folded; emits t.
// ---------------------------------------------------------------------------
__global__ void repack_k(const float* __restrict__ W, const float* __restrict__ bb,
                         const float* __restrict__ gg, const float* __restrict__ be,
                         const float* __restrict__ mm, const float* __restrict__ vv,
                         float* __restrict__ wOut, float* __restrict__ tOut,
                         int CIN, int KHW, int COUT)
{
    int gid = blockIdx.x * 256 + threadIdx.x;
    if (gid < COUT) {
        float s = gg[gid] * rsqrtf(vv[gid] + 1e-5f);
        tOut[gid] = (bb[gid] - mm[gid]) * s + be[gid];
    }
    int tot = CIN * KHW * COUT;
    if (gid >= tot) return;
    int co = gid % COUT;
    int rest = gid / COUT;
    int k = rest % KHW;
    int ci = rest / KHW;
    float s = gg[co] * rsqrtf(vv[co] + 1e-5f);
    wOut[gid] = W[(co * CIN + ci) * KHW + k] * s;
}

// ---------------------------------------------------------------------------
// MFMA B-fragment repack for 3x3 layers (conv2..conv6), fp16.
// ---------------------------------------------------------------------------
__global__ void repack_mfma_k(const float* __restrict__ W, const float* __restrict__ bb,
                              const float* __restrict__ gg, const float* __restrict__ be,
                              const float* __restrict__ mm, const float* __restrict__ vv,
                              unsigned short* __restrict__ frag, float* __restrict__ tOut,
                              int CIN, int NT, int HALVES)
{
    int gid = blockIdx.x * 256 + threadIdx.x;
    int COUT = NT * 16;
    if (gid < COUT) {
        float s = gg[gid] * rsqrtf(vv[gid] + 1e-5f);
        tOut[gid] = (bb[gid] - mm[gid]) * s + be[gid];
    }
    int tot = 9 * HALVES * NT * 512;
    if (gid >= tot) return;
    int j    = gid & 7;
    int lane = (gid >> 3) & 63;
    int nt   = (gid >> 9) % NT;
    int rest = (gid >> 9) / NT;
    int half = rest % HALVES;
    int khw  = rest / HALVES;
    int ci   = half * 32 + (lane >> 4) * 8 + j;
    int co   = nt * 16 + (lane & 15);
    int kh   = khw / 3, kw = khw % 3;
    float s = gg[co] * rsqrtf(vv[co] + 1e-5f);
    frag[gid] = f2h(W[((co * CIN + ci) * 3 + kh) * 3 + kw] * s);
}

// ---------------------------------------------------------------------------
// Conv7 weight repack into MFMA B-fragment order (12x9 kernel), fp16.
// ---------------------------------------------------------------------------
__global__ void repack7_k(const float* __restrict__ W, const float* __restrict__ bb,
                          const float* __restrict__ gg, const float* __restrict__ be,
                          const float* __restrict__ mm, const float* __restrict__ vv,
                          unsigned short* __restrict__ frag, float* __restrict__ tOut)
{
    int gid = blockIdx.x * 256 + threadIdx.x;
    if (gid < 128) {
        float s = gg[gid] * rsqrtf(vv[gid] + 1e-5f);
        tOut[gid] = (bb[gid] - mm[gid]) * s + be[gid];
    }
    if (gid >= 884736) return;           // 108*2*8*64*8
    int j    = gid & 7;
    int lane = (gid >> 3) & 63;
    int nt   = (gid >> 9) & 7;
    int half = (gid >> 12) & 1;
    int khw  = gid >> 13;
    int co   = nt * 16 + (lane & 15);
    int ci   = half * 32 + (lane >> 4) * 8 + j;
    int kh   = khw / 9, kw = khw - kh * 9;
    float s = gg[co] * rsqrtf(vv[co] + 1e-5f);
    frag[gid] = f2h(W[((co * 64 + ci) * 12 + kh) * 9 + kw] * s);
}

// ---------------------------------------------------------------------------
// FUSED conv1+conv2+conv3+conv4(+pool) per (band, sample).
// Phase 0: stage 17x24 fp32 x-slab to LDS (zero-filled for T-pad / row OOB)
//          + zero s2 halo cols.
// Phase 1: conv1 in-register (374 slab pos x 32ch) -> s1 slab. Explicit
//          window-col mask (conv SAME pad at cols -1/15 is ALWAYS zero; the
//          T-pad is a separate mask baked into the x-slab zero-fill).
// Phases 2-4: conv2 -> s2 (LDS), conv3 -> s3 (aliases s1), conv4+pool -> B.
// LDS (16B units): s1 = 4q x 375 (22r x 17c), s2 @1500 = 4 x 341 (20r x 17c),
// s3 aliases s1 = 4 x 307 (18r x 17c); sx (fp32 x-slab) after s2: 1632 B.
// ---------------------------------------------------------------------------
__global__ __launch_bounds__(256) void conv1234f_k(
    const float* __restrict__ x, unsigned short* __restrict__ out,
    const float* __restrict__ wr1, const float* __restrict__ t1v,
    const unsigned short* __restrict__ f2, const unsigned short* __restrict__ f3,
    const unsigned short* __restrict__ f4, const float* __restrict__ t2,
    const float* __restrict__ t3, const float* __restrict__ t4, int c0)
{
    __shared__ __align__(16) unsigned short sm[23728];   // 45824B slabs + sx
    float* sx = (float*)(sm + 22912);                    // 17 x 24 fp32
    const int band = blockIdx.x;
    const int nl = blockIdx.y;
    const int n = c0 + nl;
    const int tid = threadIdx.x;
    const int wave = tid >> 6, lane = tid & 63;
    const int m = lane & 15, quad = lane >> 4;
    const int b = n / 108, t = n - b * 108;

    // Phase 0: x-slab staging + s2 halo zero.
    {
        float4* dst = (float4*)sm;
        for (int i = tid; i < 568; i += 256) {
            if (i < 408) {
                int tp = i / 24, fp = i - tp * 24;
                int tt = t - 8 + tp;
                int ff = band * 16 - 4 + fp;
                float v = 0.f;
                if (tt >= 0 && tt < 108 && ff >= 0 && ff < 144)
                    v = x[(b * 108 + tt) * 144 + ff];
                sx[tp * 24 + fp] = v;
            } else {
                int j = i - 408;                 // 4q x 20r x 2cols = 160
                int q = j / 40, jj = j - q * 40;
                int rr = jj >> 1, c2 = (jj & 1) * 16;
                dst[1500 + q * 341 + rr * 17 + c2] = (float4){0.f,0.f,0.f,0.f};
            }
        }
    }
    __syncthreads();

    // Phase 1: conv1 -> s1 slab [4q][22r][17c][8].
    for (int e = tid; e < 374; e += 256) {
        int r = e / 17, cp = e - r * 17;
        int gr = band * 16 - 3 + r;
        int gc = cp - 1;
        float acc1[32];
#pragma unroll
        for (int i = 0; i < 32; ++i) acc1[i] = 0.f;
        bool valid = (gr >= 0 && gr < 144 && gc >= 0 && gc < 15);
        if (valid) {
#pragma unroll
            for (int kh = 0; kh < 3; ++kh) {
                int fp = r + kh;
#pragma unroll
                for (int kw = 0; kw < 3; ++kw) {
                    int c = gc + kw - 1;
                    if (c < 0 || c >= 15) continue;   // conv SAME pad
                    float xv = sx[(c + 1) * 24 + fp]; // T-pad zero-filled
                    const float* wp = wr1 + (kh * 3 + kw) * 32;
#pragma unroll
                    for (int q8 = 0; q8 < 8; ++q8) {
                        float4 wv = *(const float4*)(wp + q8 * 4);
                        acc1[q8 * 4 + 0] = fmaf(xv, wv.x, acc1[q8 * 4 + 0]);
                        acc1[q8 * 4 + 1] = fmaf(xv, wv.y, acc1[q8 * 4 + 1]);
                        acc1[q8 * 4 + 2] = fmaf(xv, wv.z, acc1[q8 * 4 + 2]);
                        acc1[q8 * 4 + 3] = fmaf(xv, wv.w, acc1[q8 * 4 + 3]);
                    }
                }
            }
        }
#pragma unroll
        for (int q2 = 0; q2 < 4; ++q2) {
            u16x8 pk;
#pragma unroll
            for (int c8 = 0; c8 < 8; ++c8)
                pk[c8] = valid ? f2h(fmaxf(acc1[q2 * 8 + c8] + t1v[q2 * 8 + c8], 0.f))
                               : (unsigned short)0;
            *(u16x8*)(sm + q2 * 3000 + (r * 17 + cp) * 8) = pk;
        }
    }
    __syncthreads();

    v4f acc[2][5];
    int mt[5], la[5];

    // ---------------- conv2: 20 rows x 15 cols = 300 pos, 19 tiles ----------
#pragma unroll
    for (int wt = 0; wt < 5; ++wt) {
        int tt = wave * 5 + wt; if (tt > 18) tt = 18;
        mt[wt] = tt;
        int p = tt * 16 + m; if (p >= 300) p = 299;
        int r = p / 15, c = p - r * 15;
        la[wt] = r * 17 + c;
    }
#pragma unroll
    for (int nt = 0; nt < 2; ++nt)
#pragma unroll
        for (int wt = 0; wt < 5; ++wt) acc[nt][wt] = (v4f){0.f,0.f,0.f,0.f};
#pragma unroll
    for (int khw = 0; khw < 9; ++khw) {
        const int sh = (khw / 3) * 17 + (khw % 3);
        v8h a[5];
#pragma unroll
        for (int wt = 0; wt < 5; ++wt)
            a[wt] = *(const v8h*)(sm + quad * 3000 + (la[wt] + sh) * 8);
#pragma unroll
        for (int nt = 0; nt < 2; ++nt) {
            v8h bb = *(const v8h*)(f2 + (khw * 2 + nt) * 512 + lane * 8);
#pragma unroll
            for (int wt = 0; wt < 5; ++wt)
                acc[nt][wt] = __builtin_amdgcn_mfma_f32_16x16x32_f16(a[wt], bb, acc[nt][wt], 0, 0, 0);
        }
    }
#pragma unroll
    for (int wt = 0; wt < 5; ++wt) {
        const int pb = mt[wt] * 16 + quad * 4;
#pragma unroll
        for (int nt = 0; nt < 2; ++nt) {
            const int co = nt * 16 + m;
            const float tb = t2[co];
            unsigned short* ob = sm + 12000 + (co >> 3) * 2728 + (co & 7);
#pragma unroll
            for (int reg = 0; reg < 4; ++reg) {
                int p = pb + reg;
                if (p < 300) {
                    int r = p / 15, c = p - r * 15;
                    ob[(r * 17 + c + 1) * 8] = f2h(fmaxf(acc[nt][wt][reg] + tb, 0.f));
                }
            }
        }
    }
    __syncthreads();

    // zero s3 halo cols (s3 aliases dead conv1 slab)
    if (tid < 144) {
        int q = tid / 36, jj = tid - q * 36;
        int rr = jj >> 1, c2 = (jj & 1) * 16;
        *(float4*)((float4*)sm + q * 307 + rr * 17 + c2) = (float4){0.f,0.f,0.f,0.f};
    }

    // ---------------- conv3: 18 rows x 15 cols = 270 pos, 17 tiles ----------
#pragma unroll
    for (int wt = 0; wt < 5; ++wt) {
        int tt = wave * 5 + wt; if (tt > 16) tt = 16;
        mt[wt] = tt;
        int p = tt * 16 + m; if (p >= 270) p = 269;
        int r = p / 15, c = p - r * 15;
        la[wt] = r * 17 + c;
    }
#pragma unroll
    for (int nt = 0; nt < 2; ++nt)
#pragma unroll
        for (int wt = 0; wt < 5; ++wt) acc[nt][wt] = (v4f){0.f,0.f,0.f,0.f};
#pragma unroll
    for (int khw = 0; khw < 9; ++khw) {
        const int sh = (khw / 3) * 17 + (khw % 3);
        v8h a[5];
#pragma unroll
        for (int wt = 0; wt < 5; ++wt)
            a[wt] = *(const v8h*)(sm + 12000 + quad * 2728 + (la[wt] + sh) * 8);
#pragma unroll
        for (int nt = 0; nt < 2; ++nt) {
            v8h bb = *(const v8h*)(f3 + (khw * 2 + nt) * 512 + lane * 8);
#pragma unroll
            for (int wt = 0; wt < 5; ++wt)
                acc[nt][wt] = __builtin_amdgcn_mfma_f32_16x16x32_f16(a[wt], bb, acc[nt][wt], 0, 0, 0);
        }
    }
#pragma unroll
    for (int wt = 0; wt < 5; ++wt) {
        const int pb = mt[wt] * 16 + quad * 4;
#pragma unroll
        for (int nt = 0; nt < 2; ++nt) {
            const int co = nt * 16 + m;
            const float tb = t3[co];
            unsigned short* ob = sm + (co >> 3) * 2456 + (co & 7);
#pragma unroll
            for (int reg = 0; reg < 4; ++reg) {
                int p = pb + reg;
                if (p < 270) {
                    int r = p / 15, c = p - r * 15;
                    ob[(r * 17 + c + 1) * 8] = f2h(fmaxf(acc[nt][wt][reg] + tb, 0.f));
                }
            }
        }
    }
    __syncthreads();

    // ---------------- conv4 + pool: 240 pos (pr,w,s ordered), 15 tiles ------
    int mt4[4], la4[4];
#pragma unroll
    for (int wt = 0; wt < 4; ++wt) {
        int tt = wave * 4 + wt; if (tt > 14) tt = 14;
        mt4[wt] = tt;
        int p = tt * 16 + m;
        int pr = p / 30, rem = p - pr * 30;
        int w = rem >> 1, r4 = pr * 2 + (rem & 1);
        la4[wt] = r4 * 17 + w;
    }
    v4f acc4[2][4];
#pragma unroll
    for (int nt = 0; nt < 2; ++nt)
#pragma unroll
        for (int wt = 0; wt < 4; ++wt) acc4[nt][wt] = (v4f){0.f,0.f,0.f,0.f};
#pragma unroll
    for (int khw = 0; khw < 9; ++khw) {
        const int sh = (khw / 3) * 17 + (khw % 3);
        v8h a[4];
#pragma unroll
        for (int wt = 0; wt < 4; ++wt)
            a[wt] = *(const v8h*)(sm + quad * 2456 + (la4[wt] + sh) * 8);
#pragma unroll
        for (int nt = 0; nt < 2; ++nt) {
            v8h bb = *(const v8h*)(f4 + (khw * 2 + nt) * 512 + lane * 8);
#pragma unroll
            for (int wt = 0; wt < 4; ++wt)
                acc4[nt][wt] = __builtin_amdgcn_mfma_f32_16x16x32_f16(a[wt], bb, acc4[nt][wt], 0, 0, 0);
        }
    }
    unsigned short* outN = out + (size_t)nl * SLOT;
#pragma unroll
    for (int wt = 0; wt < 4; ++wt) {
        const int pb = band * 240 + mt4[wt] * 16 + quad * 4;
#pragma unroll
        for (int nt = 0; nt < 2; ++nt) {
            const int co = nt * 16 + m;
            const float tb = t4[co];
            unsigned short* ob = outN + (co >> 3) * 9216 + (co & 7);
#pragma unroll
            for (int pi = 0; pi < 2; ++pi) {
                int pe = pb + pi * 2;
                int pr = pe / 30, rem = pe - pr * 30, w = rem >> 1;
                float v0 = fmaxf(acc4[nt][wt][pi * 2] + tb, 0.f);
                float v1 = fmaxf(acc4[nt][wt][pi * 2 + 1] + tb, 0.f);
                ob[(pr * 16 + w) * 8] = f2h(fmaxf(v0, v1));
            }
        }
    }
}

// ---------------------------------------------------------------------------
// conv5 MFMA: 32->64ch 3x3 VALID, in [4cg][72][16][8] -> out [8cg][70][16][8].
// ---------------------------------------------------------------------------
__global__ __launch_bounds__(256) void conv5m_k(
    const unsigned short* __restrict__ in, unsigned short* __restrict__ out,
    const unsigned short* __restrict__ frag, const float* __restrict__ tv)
{
    const int n = blockIdx.y;
    const int tid = threadIdx.x;
    const int wave = tid >> 6, lane = tid & 63;
    const int m = lane & 15, quad = lane >> 4;
    const unsigned short* inN = in + (size_t)n * SLOT + quad * 9216;

    int mt[2], a0[2];
#pragma unroll
    for (int wt = 0; wt < 2; ++wt) {
        int t = blockIdx.x * 8 + wave * 2 + wt; if (t > 56) t = 56;
        mt[wt] = t;
        int p = t * 16 + m; if (p > 909) p = 909;
        int r = p / 13, w = p - r * 13;
        a0[wt] = (r * 16 + w) * 8;
    }

    v4f acc[4][2];
#pragma unroll
    for (int nt = 0; nt < 4; ++nt)
#pragma unroll
        for (int wt = 0; wt < 2; ++wt) acc[nt][wt] = (v4f){0.f,0.f,0.f,0.f};

#pragma unroll
    for (int khw = 0; khw < 9; ++khw) {
        const int shift = ((khw / 3) * 16 + (khw % 3)) * 8;
        v8h a[2];
#pragma unroll
        for (int wt = 0; wt < 2; ++wt)
            a[wt] = *(const v8h*)(inN + a0[wt] + shift);
#pragma unroll
        for (int nt = 0; nt < 4; ++nt) {
            v8h b = *(const v8h*)(frag + (khw * 4 + nt) * 512 + lane * 8);
#pragma unroll
            for (int wt = 0; wt < 2; ++wt)
                acc[nt][wt] = __builtin_amdgcn_mfma_f32_16x16x32_f16(a[wt], b, acc[nt][wt], 0, 0, 0);
        }
    }

    unsigned short* outN = out + (size_t)n * SLOT;
#pragma unroll
    for (int wt = 0; wt < 2; ++wt) {
        const int pb = mt[wt] * 16 + quad * 4;
#pragma unroll
        for (int nt = 0; nt < 4; ++nt) {
            const int co = nt * 16 + m;
            const float tb = tv[co];
            unsigned short* ob = outN + (co >> 3) * 8960 + (co & 7);
#pragma unroll
            for (int reg = 0; reg < 4; ++reg) {
                int p = pb + reg;
                if (p < 910) {
                    int r = p / 13, w = p - r * 13;
                    ob[(r * 16 + w) * 8] = f2h(fmaxf(acc[nt][wt][reg] + tb, 0.f));
                }
            }
        }
    }
}

// ---------------------------------------------------------------------------
// conv6 MFMA (+fused pool) -> c6 [8cg][34r][11c][8], row stride 11.
// ---------------------------------------------------------------------------
__global__ __launch_bounds__(256) void conv6m_k(
    const unsigned short* __restrict__ in, unsigned short* __restrict__ c6,
    const unsigned short* __restrict__ frag, const float* __restrict__ tv)
{
    const int n = blockIdx.y;
    const int tid = threadIdx.x;
    const int wave = tid >> 6, lane = tid & 63;
    const int m = lane & 15, quad = lane >> 4;
    const unsigned short* inN = in + (size_t)n * SLOT;

    int mt[2], a0[2];
#pragma unroll
    for (int wt = 0; wt < 2; ++wt) {
        int t = blockIdx.x * 8 + wave * 2 + wt; if (t > 46) t = 46;
        mt[wt] = t;
        int p = t * 16 + m; if (p > 747) p = 747;
        int pr = p / 22, rem = p - pr * 22;
        int w = rem >> 1, r = pr * 2 + (rem & 1);
        a0[wt] = (r * 16 + w) * 8;
    }

    v4f acc[4][2];
#pragma unroll
    for (int nt = 0; nt < 4; ++nt)
#pragma unroll
        for (int wt = 0; wt < 2; ++wt) acc[nt][wt] = (v4f){0.f,0.f,0.f,0.f};

#pragma unroll
    for (int khw = 0; khw < 9; ++khw) {
        const int shift = ((khw / 3) * 16 + (khw % 3)) * 8;
#pragma unroll
        for (int half = 0; half < 2; ++half) {
            const unsigned short* ip = inN + (half * 4 + quad) * 8960 + shift;
            v8h a[2];
#pragma unroll
            for (int wt = 0; wt < 2; ++wt)
                a[wt] = *(const v8h*)(ip + a0[wt]);
#pragma unroll
            for (int nt = 0; nt < 4; ++nt) {
                v8h b = *(const v8h*)(frag + ((khw * 2 + half) * 4 + nt) * 512 + lane * 8);
#pragma unroll
                for (int wt = 0; wt < 2; ++wt)
                    acc[nt][wt] = __builtin_amdgcn_mfma_f32_16x16x32_f16(a[wt], b, acc[nt][wt], 0, 0, 0);
            }
        }
    }

    unsigned short* outN = c6 + (size_t)n * C6N;
#pragma unroll
    for (int wt = 0; wt < 2; ++wt) {
        const int pb = mt[wt] * 16 + quad * 4;
#pragma unroll
        for (int nt = 0; nt < 4; ++nt) {
            const int co = nt * 16 + m;
            const float tb = tv[co];
            unsigned short* ob = outN + (co >> 3) * 2992 + (co & 7);
#pragma unroll
            for (int pi = 0; pi < 2; ++pi) {
                int pe = pb + pi * 2;
                if (pe < 748) {
                    int pr = pe / 22, rem = pe - pr * 22, w = rem >> 1;
                    float v0 = fmaxf(acc[nt][wt][pi * 2] + tb, 0.f);
                    float v1 = fmaxf(acc[nt][wt][pi * 2 + 1] + tb, 0.f);
                    ob[(pr * 11 + w) * 8] = f2h(fmaxf(v0, v1));
                }
            }
        }
    }
}

// ---------------------------------------------------------------------------
// Conv7 MFMA GEMM — R12-measured-best config (48 VGPR, 42% occ, 196us):
// LDS 443 quad stride / 13 row stride; staging remaps from stride-11 c6.
// (R13's stride-11 LDS halved conflicts but cost VGPR 60 / occ 34% -> net loss.)
// ---------------------------------------------------------------------------
__global__ __launch_bounds__(256) void conv7mfma_k(
    const unsigned short* __restrict__ c6, float* __restrict__ pooled,
    const unsigned short* __restrict__ frag7, const float* __restrict__ tv)
{
    __shared__ __align__(16) unsigned short sA[14176];  // 4 x 443 x 8
    const int n = blockIdx.x;
    const int tid = threadIdx.x;
    const int wave = tid >> 6;
    const int lane = tid & 63;
    const int m = lane & 15;
    const int quad = lane >> 4;

    int pm[5];
#pragma unroll
    for (int mt = 0; mt < 5; ++mt) {
        int p = mt * 16 + m;
        if (p >= 69) p = 0;
        pm[mt] = (p / 3) * 13 + (p % 3);
    }

    v4f acc[2][5];
#pragma unroll
    for (int t = 0; t < 2; ++t)
#pragma unroll
        for (int mt = 0; mt < 5; ++mt)
            acc[t][mt] = (v4f){0.f, 0.f, 0.f, 0.f};

    for (int half = 0; half < 2; ++half) {
        __syncthreads();
        {
            const float4* src = (const float4*)(c6 + (size_t)n * C6N + half * 11968);
            float4* dst = (float4*)sA;
            for (int i = tid; i < 1496; i += 256) {
                int q = i / 374, pos = i - q * 374;
                int h = pos / 11, w = pos - h * 11;
                dst[q * 443 + h * 13 + w] = src[i];
            }
        }
        __syncthreads();
        for (int khw = 0; khw < 108; ++khw) {
            const int off = (khw / 9) * 13 + (khw % 9);
            v8h a[5];
#pragma unroll
            for (int mt = 0; mt < 5; ++mt)
                a[mt] = *(const v8h*)(sA + (quad * 443 + pm[mt] + off) * 8);
            const unsigned short* bp = frag7
                + ((size_t)(khw * 2 + half) * 8) * 512 + lane * 8;
#pragma unroll
            for (int t = 0; t < 2; ++t) {
                const int nt = wave + t * 4;
                v8h b = *(const v8h*)(bp + nt * 512);
#pragma unroll
                for (int mt = 0; mt < 5; ++mt)
                    acc[t][mt] = __builtin_amdgcn_mfma_f32_16x16x32_f16(
                        a[mt], b, acc[t][mt], 0, 0, 0);
            }
        }
    }

    float s[2] = {0.f, 0.f};
#pragma unroll
    for (int t = 0; t < 2; ++t) {
        const float tb = tv[(wave + t * 4) * 16 + m];
#pragma unroll
        for (int mt = 0; mt < 5; ++mt) {
#pragma unroll
            for (int rr = 0; rr < 4; ++rr) {
                int p = mt * 16 + quad * 4 + rr;
                if (p < 69) s[t] += fmaxf(acc[t][mt][rr] + tb, 0.f);
            }
        }
    }
#pragma unroll
    for (int t = 0; t < 2; ++t) {
        s[t] += __shfl_xor(s[t], 16);
        s[t] += __shfl_xor(s[t], 32);
    }
    if (lane < 16) {
#pragma unroll
        for (int t = 0; t < 2; ++t)
            pooled[(size_t)n * 128 + (wave + t * 4) * 16 + lane] = s[t] * (1.f / 69.f);
    }
}

// ---------------------------------------------------------------------------
// logits = b8 + W8(25x128) . pooled
// ---------------------------------------------------------------------------
__global__ void logits_k(const float* __restrict__ pooled, const float* __restrict__ W8,
                         const float* __restrict__ b8, float* __restrict__ outg,
                         int total)
{
    int gid = blockIdx.x * 256 + threadIdx.x;
    if (gid >= total * 25) return;
    int nl = gid / 25, c = gid - nl * 25;
    const float* pp = pooled + (size_t)nl * 128;
    const float* wp = W8 + c * 128;
    float s = b8[c];
#pragma unroll
    for (int ci = 0; ci < 128; ci += 4) {
        float4 wv = *(const float4*)(wp + ci);
        float4 pv = *(const float4*)(pp + ci);
        s = fmaf(wv.x, pv.x, s);
        s = fmaf(wv.y, pv.y, s);
        s = fmaf(wv.z, pv.z, s);
        s = fmaf(wv.w, pv.w, s);
    }
    outg[(size_t)nl * 25 + c] = s;
}

// ---------------------------------------------------------------------------
extern "C" void kernel_launch(void* const* d_in, const int* in_sizes, int n_in,
                              void* d_out, int out_size, void* d_ws, size_t ws_size,
                              hipStream_t stream)
{
    const float* x = (const float*)d_in[0];
    const float* Wl[8]; const float* bl[8]; const float* gl[8];
    const float* bel[8]; const float* ml[8]; const float* vl[8];
    for (int i = 1; i <= 7; ++i) {
        int o = 2 + (i - 1) * 6;
        Wl[i]  = (const float*)d_in[o + 0];
        bl[i]  = (const float*)d_in[o + 1];
        gl[i]  = (const float*)d_in[o + 2];
        bel[i] = (const float*)d_in[o + 3];
        ml[i]  = (const float*)d_in[o + 4];
        vl[i]  = (const float*)d_in[o + 5];
    }
    const float* W8 = (const float*)d_in[44];
    const float* b8 = (const float*)d_in[45];
    float* ws = (float*)d_ws;

    // Workspace layout (float offsets); all 16B aligned.
    float* wr1 = ws + 0;        float* t1 = ws + 288;
    unsigned short* f2b = (unsigned short*)(ws + 320);
    float* t2 = ws + 4928;
    unsigned short* f3b = (unsigned short*)(ws + 4960);
    float* t3 = ws + 9568;
    unsigned short* f4b = (unsigned short*)(ws + 9600);
    float* t4 = ws + 14208;
    unsigned short* f5b = (unsigned short*)(ws + 14240);
    float* t5 = ws + 23456;
    unsigned short* f6b = (unsigned short*)(ws + 23520);
    float* t6 = ws + 41952;
    unsigned short* f7b = (unsigned short*)(ws + 42016);
    float* t7 = ws + 484384;
    const size_t WFL = 484512;

    // Persistent: c6 ([n][8cg][34r][11c][8] fp16) + pooled (fp32).
    unsigned short* c6buf = (unsigned short*)(ws + WFL);
    const size_t C6FL = (size_t)1728 * C6N / 2;
    float* pooled = ws + WFL + C6FL;
    const size_t FIXED = WFL + C6FL + (size_t)1728 * 128;

    size_t avail_fl = ws_size / 4;
    size_t buf_halves = (avail_fl > FIXED) ? (avail_fl - FIXED) * 2 : 0;
    int Cs = (int)(buf_halves / (size_t)SLOT);
    if (Cs < 1) Cs = 1;
    if (Cs > 1728) Cs = 1728;
    unsigned short* bufA = (unsigned short*)(ws + FIXED);   // region A (off 0)
    unsigned short* bufB = bufA + TA;                        // region B (off TA)

    auto g1 = [](int t) { return (t + 255) / 256; };

    // Weight repacks (once per call)
    repack_k<<<g1(288), 256, 0, stream>>>(Wl[1], bl[1], gl[1], bel[1], ml[1], vl[1], wr1, t1, 1, 9, 32);
    repack_mfma_k<<<g1(9216),  256, 0, stream>>>(Wl[2], bl[2], gl[2], bel[2], ml[2], vl[2], f2b, t2, 32, 2, 1);
    repack_mfma_k<<<g1(9216),  256, 0, stream>>>(Wl[3], bl[3], gl[3], bel[3], ml[3], vl[3], f3b, t3, 32, 2, 1);
    repack_mfma_k<<<g1(9216),  256, 0, stream>>>(Wl[4], bl[4], gl[4], bel[4], ml[4], vl[4], f4b, t4, 32, 2, 1);
    repack_mfma_k<<<g1(18432), 256, 0, stream>>>(Wl[5], bl[5], gl[5], bel[5], ml[5], vl[5], f5b, t5, 32, 4, 1);
    repack_mfma_k<<<g1(36864), 256, 0, stream>>>(Wl[6], bl[6], gl[6], bel[6], ml[6], vl[6], f6b, t6, 64, 4, 2);
    repack7_k<<<g1(884736), 256, 0, stream>>>(Wl[7], bl[7], gl[7], bel[7], ml[7], vl[7], f7b, t7);

    // Stage 1 (chunked, tight layouts):
    // fused conv1/2/3/4 x->B, conv5 B->A, conv6 A->c6
    for (int c0 = 0; c0 < 1728; c0 += Cs) {
        int cn = (1728 - c0 < Cs) ? (1728 - c0) : Cs;
        conv1234f_k<<<dim3(9, cn), 256, 0, stream>>>(x, bufB, wr1, t1,
                                                     f2b, f3b, f4b, t2, t3, t4, c0);
        conv5m_k<<<dim3(8, cn), 256, 0, stream>>>(bufB, bufA, f5b, t5);
        conv6m_k<<<dim3(6, cn), 256, 0, stream>>>(bufA, c6buf + (size_t)c0 * C6N, f6b, t6);
    }

    // Stage 2: conv7 MFMA (+bias+relu+mean) over all samples, then logits.
    conv7mfma_k<<<1728, 256, 0, stream>>>(c6buf, pooled, f7b, t7);
    logits_k<<<g1(1728 * 25), 256, 0, stream>>>(pooled, W8, b8, (float*)d_out, 1728);
}